// Round 5
// baseline (255.438 us; speedup 1.0000x reference)
//
#include <hip/hip_runtime.h>
#include <hip/hip_bf16.h>

typedef short short8 __attribute__((ext_vector_type(8)));
typedef float f32x4 __attribute__((ext_vector_type(4)));
typedef unsigned int uint4v __attribute__((ext_vector_type(4)));

__device__ __forceinline__ short f2bf(float f) {
  unsigned u = __builtin_bit_cast(unsigned, f);
  u += 0x7fffu + ((u >> 16) & 1u);          // RNE
  return (short)(u >> 16);
}
__device__ __forceinline__ float bf2f(short s) {
  unsigned u = ((unsigned)(unsigned short)s) << 16;
  return __builtin_bit_cast(float, u);
}
__device__ __forceinline__ unsigned pk2(float a, float b) {
  __hip_bfloat162 h = __float22bfloat162_rn(float2{a, b});
  unsigned u;
  __builtin_memcpy(&u, &h, 4);
  return u;
}
__device__ __forceinline__ void gl_lds16(const void* g, void* l) {
  __builtin_amdgcn_global_load_lds(
      (const __attribute__((address_space(1))) unsigned int*)g,
      (__attribute__((address_space(3))) unsigned int*)l, 16, 0, 0);
}

#define QSTRIDE 576

// ---------------- W transpose + bf16 convert: Wt[z][n][k] -------------------
__global__ __launch_bounds__(256) void wt_kernel(
    const float* __restrict__ WQ, const float* __restrict__ WK, const float* __restrict__ WV,
    short* __restrict__ Wt)
{
  const int z = blockIdx.z;
  const float* W = (z == 0) ? WQ : (z == 1) ? WK : WV;
  short* o = Wt + (size_t)z * 512 * 512;
  __shared__ short t[64][65];
  const int k0 = blockIdx.y * 64, n0 = blockIdx.x * 64;
  const int c = threadIdx.x & 63, rb = threadIdx.x >> 6;
#pragma unroll
  for (int p = 0; p < 16; ++p) {
    const int kk = p * 4 + rb;
    t[kk][c] = f2bf(W[(size_t)(k0 + kk) * 512 + n0 + c]);
  }
  __syncthreads();
#pragma unroll
  for (int p = 0; p < 16; ++p) {
    const int nn = p * 4 + rb;
    o[(size_t)(n0 + nn) * 512 + k0 + c] = t[c][nn];
  }
}

// ---------------- Projection GEMM, 256x256 tile, 8 waves --------------------
// logical: z (0..2), row0 (0..127)*256, col0 (0..1)*256  -> 768 blocks
__global__ __launch_bounds__(512) void proj_kernel(
    const float* __restrict__ Q, const float* __restrict__ Kin, const float* __restrict__ Vin,
    const short* __restrict__ Wt,
    const float* __restrict__ bQ, const float* __restrict__ bK, const float* __restrict__ bV,
    short* __restrict__ qbuf, short* __restrict__ kp, short* __restrict__ vp)
{
  const int phys = blockIdx.x;
  const int log_ = (phys & 7) * 96 + (phys >> 3);     // 768 = 8 * 96, bijective
  const int z = log_ >> 8;                            // 256 blocks per z
  const int rem = log_ & 255;
  const int row0 = (rem >> 1) * 256;
  const int col0 = (rem & 1) * 256;

  const float* X    = (z == 0) ? Q  : (z == 1) ? Kin : Vin;
  const float* bias = (z == 0) ? bQ : (z == 1) ? bK  : bV;
  const short* Wz   = Wt + (size_t)z * 512 * 512;

  __shared__ short a_lds[2][256 * 32];
  __shared__ short b_lds[2][256 * 32];

  const int tid = threadIdx.x;
  const int lane = tid & 63, wv = tid >> 6;
  const int wr = wv >> 2, wc = wv & 3;                // wave tile: 128 x 64
  const int fr = lane & 15, fg = lane >> 4;

  f32x4 acc[8][4];
#pragma unroll
  for (int i = 0; i < 8; ++i)
#pragma unroll
    for (int j = 0; j < 4; ++j) acc[i][j] = (f32x4){0.f, 0.f, 0.f, 0.f};

  const int ar = tid >> 1;            // A staging row (0..255)
  const int ak = (tid & 1) * 16;      // A staging k-offset (16 elems)
  const int bl8 = lane * 8;           // lane's 8-elem offset within wave's LDS chunk

  // ---- prologue: tile 0 -> buf 0
  {
#pragma unroll
    for (int i = 0; i < 2; ++i) {
      const int nb = i * 128 + wv * 16;
      gl_lds16(Wz + (size_t)(col0 + nb + (lane >> 2)) * 512 + (lane & 3) * 8,
               &b_lds[0][nb * 32 + bl8]);
    }
    const f32x4* ap = (const f32x4*)(X + (size_t)(row0 + ar) * 512 + ak);
    f32x4 f0 = ap[0], f1 = ap[1], f2 = ap[2], f3 = ap[3];
    uint4v s0, s1;
    s0[0] = pk2(f0[0], f0[1]); s0[1] = pk2(f0[2], f0[3]);
    s0[2] = pk2(f1[0], f1[1]); s0[3] = pk2(f1[2], f1[3]);
    s1[0] = pk2(f2[0], f2[1]); s1[1] = pk2(f2[2], f2[3]);
    s1[2] = pk2(f3[0], f3[1]); s1[3] = pk2(f3[2], f3[3]);
    *(uint4v*)&a_lds[0][ar * 32 + ak] = s0;          // wait: ak is 0 or 16
    *(uint4v*)&a_lds[0][ar * 32 + ak + 8] = s1;
  }
  __syncthreads();

  for (int t = 0; t < 16; ++t) {
    const int cur = t & 1;
    const bool pf = (t < 15);
    f32x4 p0, p1, p2, p3;
    if (pf) {
      const int k1 = (t + 1) * 32;
      short* bn = b_lds[cur ^ 1];
#pragma unroll
      for (int i = 0; i < 2; ++i) {
        const int nb = i * 128 + wv * 16;
        gl_lds16(Wz + (size_t)(col0 + nb + (lane >> 2)) * 512 + k1 + (lane & 3) * 8,
                 &bn[nb * 32 + bl8]);
      }
      const f32x4* ap = (const f32x4*)(X + (size_t)(row0 + ar) * 512 + k1 + ak);
      p0 = ap[0]; p1 = ap[1]; p2 = ap[2]; p3 = ap[3];
    }

    const short* acur = a_lds[cur];
    const short* bcur = b_lds[cur];
    short8 af[8], bfr[4];
#pragma unroll
    for (int mi = 0; mi < 8; ++mi)
      af[mi] = *(const short8*)&acur[(wr * 128 + mi * 16 + fr) * 32 + fg * 8];
#pragma unroll
    for (int ni = 0; ni < 4; ++ni)
      bfr[ni] = *(const short8*)&bcur[(wc * 64 + ni * 16 + fr) * 32 + fg * 8];
#pragma unroll
    for (int mi = 0; mi < 8; ++mi)
#pragma unroll
      for (int ni = 0; ni < 4; ++ni)
        acc[mi][ni] = __builtin_amdgcn_mfma_f32_16x16x32_bf16(af[mi], bfr[ni], acc[mi][ni], 0, 0, 0);

    if (pf) {
      short* an = a_lds[cur ^ 1];
      uint4v s0, s1;
      s0[0] = pk2(p0[0], p0[1]); s0[1] = pk2(p0[2], p0[3]);
      s0[2] = pk2(p1[0], p1[1]); s0[3] = pk2(p1[2], p1[3]);
      s1[0] = pk2(p2[0], p2[1]); s1[1] = pk2(p2[2], p2[3]);
      s1[2] = pk2(p3[0], p3[1]); s1[3] = pk2(p3[2], p3[3]);
      *(uint4v*)&an[ar * 32 + ak] = s0;
      *(uint4v*)&an[ar * 32 + ak + 8] = s1;
    }
    __syncthreads();
  }

#pragma unroll
  for (int ni = 0; ni < 4; ++ni) {
    const int gc = col0 + wc * 64 + ni * 16 + fr;
    const float bv = bias[gc];
#pragma unroll
    for (int mi = 0; mi < 8; ++mi) {
#pragma unroll
      for (int r = 0; r < 4; ++r) {
        const int gr = row0 + wr * 128 + mi * 16 + fg * 4 + r;
        const short b = f2bf(acc[mi][ni][r] + bv);
        if (z == 0) {
          const int h = gc >> 5, j = gc & 31;
          qbuf[(size_t)gr * QSTRIDE + h * 34 + 2 + j] = b;
        } else if (z == 1) {
          kp[(size_t)gr * 512 + gc] = b;
        } else {
          vp[(size_t)gr * 512 + gc] = b;
        }
      }
    }
  }
}

// ---------------- pos columns + zero pad of qbuf ----------------------------
__global__ __launch_bounds__(256) void fillpos_kernel(
    const float* __restrict__ pos, short* __restrict__ qbuf)
{
  const int i = blockIdx.x * 256 + threadIdx.x;
  const short b0 = f2bf(pos[(size_t)i * 2]);
  const short b1 = f2bf(pos[(size_t)i * 2 + 1]);
  short* row = qbuf + (size_t)i * QSTRIDE;
#pragma unroll
  for (int h = 0; h < 16; ++h) { row[h * 34] = b0; row[h * 34 + 1] = b1; }
  const short8 zz = (short8){0,0,0,0,0,0,0,0};
#pragma unroll
  for (int p = 0; p < 4; ++p) ((short8*)(row + 544))[p] = zz;
}

// ---------------- LN + ktv accumulation ------------------------------------
#define SC 256
#define TP 264

__global__ __launch_bounds__(256) void ktv_kernel(
    const short* __restrict__ kp, const short* __restrict__ vp,
    const float* __restrict__ pos,
    const float* __restrict__ lnwK, const float* __restrict__ lnbK,
    const float* __restrict__ lnwV, const float* __restrict__ lnbV,
    float* __restrict__ ktv)
{
  const int nh = blockIdx.y;
  const int n = nh >> 4, h = nh & 15;
  const int s0 = blockIdx.x * SC;
  const int tid = threadIdx.x;

  __shared__ short klds[48 * TP];
  __shared__ short vlds[48 * TP];
  __shared__ float lw[2][32], lb[2][32];

  if (tid < 32) {
    lw[0][tid] = lnwK[h * 32 + tid]; lb[0][tid] = lnbK[h * 32 + tid];
    lw[1][tid] = lnwV[h * 32 + tid]; lb[1][tid] = lnbV[h * 32 + tid];
  }
  __syncthreads();

  const size_t rowix = (size_t)n * 8192 + (s0 + tid);
  {
    const short8* src = (const short8*)(kp + rowix * 512 + h * 32);
    short8 r0 = src[0], r1 = src[1], r2 = src[2], r3 = src[3];
    float x[32];
#pragma unroll
    for (int i = 0; i < 8; ++i) { x[i] = bf2f(r0[i]); x[8+i] = bf2f(r1[i]); x[16+i] = bf2f(r2[i]); x[24+i] = bf2f(r3[i]); }
    float mu = 0.f;
#pragma unroll
    for (int i = 0; i < 32; ++i) mu += x[i];
    mu *= (1.f / 32.f);
    float var = 0.f;
#pragma unroll
    for (int i = 0; i < 32; ++i) { float d = x[i] - mu; var += d * d; }
    var *= (1.f / 32.f);
    const float rstd = rsqrtf(var + 1e-5f);
#pragma unroll
    for (int d = 0; d < 32; ++d)
      klds[d * TP + tid] = f2bf((x[d] - mu) * rstd * lw[0][d] + lb[0][d]);
  }
  {
    const short8* src = (const short8*)(vp + rowix * 512 + h * 32);
    short8 r0 = src[0], r1 = src[1], r2 = src[2], r3 = src[3];
    float x[32];
#pragma unroll
    for (int i = 0; i < 8; ++i) { x[i] = bf2f(r0[i]); x[8+i] = bf2f(r1[i]); x[16+i] = bf2f(r2[i]); x[24+i] = bf2f(r3[i]); }
    float mu = 0.f;
#pragma unroll
    for (int i = 0; i < 32; ++i) mu += x[i];
    mu *= (1.f / 32.f);
    float var = 0.f;
#pragma unroll
    for (int i = 0; i < 32; ++i) { float d = x[i] - mu; var += d * d; }
    var *= (1.f / 32.f);
    const float rstd = rsqrtf(var + 1e-5f);
#pragma unroll
    for (int d = 0; d < 32; ++d)
      vlds[d * TP + tid] = f2bf((x[d] - mu) * rstd * lw[1][d] + lb[1][d]);
  }
  {
    const short p0 = f2bf(pos[rowix * 2]);
    const short p1 = f2bf(pos[rowix * 2 + 1]);
    klds[32 * TP + tid] = p0; klds[33 * TP + tid] = p1;
    vlds[32 * TP + tid] = p0; vlds[33 * TP + tid] = p1;
  }
  __syncthreads();

  const int wv = tid >> 6, lane = tid & 63;
  if (wv < 3) {
    const int fr = lane & 15, fg = lane >> 4;
    f32x4 acc[3];
#pragma unroll
    for (int i = 0; i < 3; ++i) acc[i] = (f32x4){0.f, 0.f, 0.f, 0.f};
    for (int kk = 0; kk < SC; kk += 32) {
      short8 a = *(const short8*)&klds[(wv * 16 + fr) * TP + kk + fg * 8];
#pragma unroll
      for (int ni = 0; ni < 3; ++ni) {
        short8 b = *(const short8*)&vlds[(ni * 16 + fr) * TP + kk + fg * 8];
        acc[ni] = __builtin_amdgcn_mfma_f32_16x16x32_bf16(a, b, acc[ni], 0, 0, 0);
      }
    }
#pragma unroll
    for (int ni = 0; ni < 3; ++ni) {
      const int ei = ni * 16 + fr;
      if (ei < 34) {
        const int er = (ei < 32) ? ei + 2 : ei - 32;
#pragma unroll
        for (int r = 0; r < 4; ++r) {
          const int di = wv * 16 + fg * 4 + r;
          if (di < 34) {
            const int dr = (di < 32) ? di + 2 : di - 32;
            atomicAdd(&ktv[((size_t)nh * 34 + dr) * 34 + er], acc[ni][r]);
          }
        }
      }
    }
  }
}

// -------- Mt[n][o][c] = sum_e ktv[n,h(c),d(c),e]/S * fcW[o][h*34+e], bf16 ---
__global__ __launch_bounds__(256) void mmk_kernel(
    const float* __restrict__ ktv, const float* __restrict__ fcW,
    short* __restrict__ Mt)
{
  const int n = blockIdx.y;
  const int o = blockIdx.x;
  __shared__ float w[544];
  __shared__ float kv[16 * 34 * 34];
  for (int i = threadIdx.x; i < 544; i += 256) w[i] = fcW[(size_t)o * 544 + i];
  for (int i = threadIdx.x; i < 16 * 34 * 34; i += 256)
    kv[i] = ktv[(size_t)n * 16 * 34 * 34 + i] * (1.0f / 8192.0f);
  __syncthreads();
  for (int c = threadIdx.x; c < QSTRIDE; c += 256) {
    short val = 0;
    if (c < 544) {
      const int h = c / 34, d = c - h * 34;
      const float* kr = &kv[(h * 34 + d) * 34];
      const float* wr = &w[h * 34];
      float acc = 0.f;
#pragma unroll
      for (int e = 0; e < 34; ++e) acc += kr[e] * wr[e];
      val = f2bf(acc);
    }
    Mt[((size_t)n * 512 + o) * QSTRIDE + c] = val;
  }
}

// ---------------- final GEMM: 256x256 tile, 8 waves -------------------------
// logical: n (0..3), row0 (0..31)*256, col0 (0..1)*256 -> 256 blocks
__global__ __launch_bounds__(512) void fgemm_kernel(
    const short* __restrict__ qbuf, const short* __restrict__ Mt,
    const float* __restrict__ fcb, float* __restrict__ out)
{
  const int phys = blockIdx.x;
  const int log_ = (phys & 7) * 32 + (phys >> 3);     // 256 = 8 * 32
  const int n = log_ >> 6;
  const int rem = log_ & 63;
  const int row0 = (rem >> 1) * 256;
  const int col0 = (rem & 1) * 256;

  const short* A = qbuf + (size_t)n * 8192 * QSTRIDE;
  const short* B = Mt + (size_t)n * 512 * QSTRIDE;

  __shared__ short a_lds[2][256 * 32];
  __shared__ short b_lds[2][256 * 32];

  const int tid = threadIdx.x;
  const int lane = tid & 63, wv = tid >> 6;
  const int wr = wv >> 2, wc = wv & 3;
  const int fr = lane & 15, fg = lane >> 4;
  const int bl8 = lane * 8;

  f32x4 acc[8][4];
#pragma unroll
  for (int i = 0; i < 8; ++i)
#pragma unroll
    for (int j = 0; j < 4; ++j) acc[i][j] = (f32x4){0.f, 0.f, 0.f, 0.f};

  // prologue: tile 0 -> buf 0
#pragma unroll
  for (int i = 0; i < 2; ++i) {
    const int nb = i * 128 + wv * 16;
    gl_lds16(A + (size_t)(row0 + nb + (lane >> 2)) * QSTRIDE + (lane & 3) * 8,
             &a_lds[0][nb * 32 + bl8]);
    gl_lds16(B + (size_t)(col0 + nb + (lane >> 2)) * QSTRIDE + (lane & 3) * 8,
             &b_lds[0][nb * 32 + bl8]);
  }
  __syncthreads();

  for (int t = 0; t < 18; ++t) {
    const int cur = t & 1;
    if (t < 17) {
      const int k1 = (t + 1) * 32;
      short* an = a_lds[cur ^ 1];
      short* bn = b_lds[cur ^ 1];
#pragma unroll
      for (int i = 0; i < 2; ++i) {
        const int nb = i * 128 + wv * 16;
        gl_lds16(A + (size_t)(row0 + nb + (lane >> 2)) * QSTRIDE + k1 + (lane & 3) * 8,
                 &an[nb * 32 + bl8]);
        gl_lds16(B + (size_t)(col0 + nb + (lane >> 2)) * QSTRIDE + k1 + (lane & 3) * 8,
                 &bn[nb * 32 + bl8]);
      }
    }
    const short* acur = a_lds[cur];
    const short* bcur = b_lds[cur];
    short8 af[8], bfr[4];
#pragma unroll
    for (int mi = 0; mi < 8; ++mi)
      af[mi] = *(const short8*)&acur[(wr * 128 + mi * 16 + fr) * 32 + fg * 8];
#pragma unroll
    for (int ni = 0; ni < 4; ++ni)
      bfr[ni] = *(const short8*)&bcur[(wc * 64 + ni * 16 + fr) * 32 + fg * 8];
#pragma unroll
    for (int mi = 0; mi < 8; ++mi)
#pragma unroll
      for (int ni = 0; ni < 4; ++ni)
        acc[mi][ni] = __builtin_amdgcn_mfma_f32_16x16x32_bf16(af[mi], bfr[ni], acc[mi][ni], 0, 0, 0);
    __syncthreads();
  }

#pragma unroll
  for (int ni = 0; ni < 4; ++ni) {
    const int gc = col0 + wc * 64 + ni * 16 + fr;
    const float bv = fcb[gc];
#pragma unroll
    for (int mi = 0; mi < 8; ++mi)
#pragma unroll
      for (int r = 0; r < 4; ++r) {
        const int gr = row0 + wr * 128 + mi * 16 + fg * 4 + r;
        out[((size_t)n * 8192 + gr) * 512 + gc] = acc[mi][ni][r] + bv;
      }
  }
}

// ---------------------------------------------------------------------------
extern "C" void kernel_launch(void* const* d_in, const int* in_sizes, int n_in,
                              void* d_out, int out_size, void* d_ws, size_t ws_size,
                              hipStream_t stream) {
  const float* Q    = (const float*)d_in[0];
  const float* Kin  = (const float*)d_in[1];
  const float* Vin  = (const float*)d_in[2];
  const float* pos  = (const float*)d_in[3];
  const float* WQ   = (const float*)d_in[4];
  const float* WK   = (const float*)d_in[5];
  const float* WV   = (const float*)d_in[6];
  const float* bQ   = (const float*)d_in[7];
  const float* bK   = (const float*)d_in[8];
  const float* bV   = (const float*)d_in[9];
  const float* lnwK = (const float*)d_in[10];
  const float* lnbK = (const float*)d_in[11];
  const float* lnwV = (const float*)d_in[12];
  const float* lnbV = (const float*)d_in[13];
  const float* fcW  = (const float*)d_in[14];
  const float* fcb  = (const float*)d_in[15];

  char* ws = (char*)d_ws;
  const size_t QBUF_B = (size_t)4 * 8192 * QSTRIDE * 2;
  const size_t KP_B   = (size_t)4 * 8192 * 512 * 2;
  const size_t KTV_B  = (size_t)64 * 34 * 34 * 4;
  const size_t MT_B   = (size_t)4 * 512 * QSTRIDE * 2;
  short* qbuf = (short*)ws;
  short* kp   = (short*)(ws + QBUF_B);
  short* vp   = (short*)(ws + QBUF_B + KP_B);
  float* ktv  = (float*)(ws + QBUF_B + 2 * KP_B);
  short* Mt   = (short*)(ws + QBUF_B + 2 * KP_B + KTV_B);
  short* Wt   = (short*)(ws + QBUF_B + 2 * KP_B + KTV_B + MT_B);

  (void)hipMemsetAsync(ktv, 0, KTV_B, stream);
  hipLaunchKernelGGL(wt_kernel, dim3(8, 8, 3), dim3(256), 0, stream, WQ, WK, WV, Wt);
  hipLaunchKernelGGL(proj_kernel, dim3(768), dim3(512), 0, stream,
                     Q, Kin, Vin, Wt, bQ, bK, bV, qbuf, kp, vp);
  hipLaunchKernelGGL(fillpos_kernel, dim3(128), dim3(256), 0, stream, pos, qbuf);
  hipLaunchKernelGGL(ktv_kernel, dim3(32, 64), dim3(256), 0, stream,
                     kp, vp, pos, lnwK, lnbK, lnwV, lnbV, ktv);
  hipLaunchKernelGGL(mmk_kernel, dim3(512, 4), dim3(256), 0, stream, ktv, fcW, Mt);
  hipLaunchKernelGGL(fgemm_kernel, dim3(256), dim3(512), 0, stream,
                     qbuf, Mt, fcb, (float*)d_out);
}

// Round 6
// 231.738 us; speedup vs baseline: 1.1023x; 1.1023x over previous
//
#include <hip/hip_runtime.h>
#include <hip/hip_bf16.h>

typedef short short8 __attribute__((ext_vector_type(8)));
typedef float f32x4 __attribute__((ext_vector_type(4)));
typedef unsigned int uint4v __attribute__((ext_vector_type(4)));

__device__ __forceinline__ short f2bf(float f) {
  unsigned u = __builtin_bit_cast(unsigned, f);
  u += 0x7fffu + ((u >> 16) & 1u);          // RNE
  return (short)(u >> 16);
}
__device__ __forceinline__ float bf2f(short s) {
  unsigned u = ((unsigned)(unsigned short)s) << 16;
  return __builtin_bit_cast(float, u);
}
__device__ __forceinline__ unsigned pk2(float a, float b) {
  __hip_bfloat162 h = __float22bfloat162_rn(float2{a, b});
  unsigned u;
  __builtin_memcpy(&u, &h, 4);
  return u;
}
__device__ __forceinline__ void gl_lds16(const void* g, void* l) {
  __builtin_amdgcn_global_load_lds(
      (const __attribute__((address_space(1))) unsigned int*)g,
      (__attribute__((address_space(3))) unsigned int*)l, 16, 0, 0);
}

// ---------------- W transpose + bf16: Wt[z][n][k], z=0:WK z=1:WV ------------
__global__ __launch_bounds__(256) void wt_kernel(
    const float* __restrict__ WK, const float* __restrict__ WV,
    short* __restrict__ Wt)
{
  const int z = blockIdx.z;
  const float* W = (z == 0) ? WK : WV;
  short* o = Wt + (size_t)z * 512 * 512;
  __shared__ short t[64][65];
  const int k0 = blockIdx.y * 64, n0 = blockIdx.x * 64;
  const int c = threadIdx.x & 63, rb = threadIdx.x >> 6;
#pragma unroll
  for (int p = 0; p < 16; ++p) {
    const int kk = p * 4 + rb;
    t[kk][c] = f2bf(W[(size_t)(k0 + kk) * 512 + n0 + c]);
  }
  __syncthreads();
#pragma unroll
  for (int p = 0; p < 16; ++p) {
    const int nn = p * 4 + rb;
    o[(size_t)(n0 + nn) * 512 + k0 + c] = t[c][nn];
  }
}

// ---------------- K/V projection GEMM, 256x256 tile, 8 waves ----------------
// logical: z (0..1), row0 (0..127)*256, col0 (0..1)*256 -> 512 blocks
__global__ __launch_bounds__(512) void proj_kernel(
    const float* __restrict__ Kin, const float* __restrict__ Vin,
    const short* __restrict__ Wt,
    const float* __restrict__ bK, const float* __restrict__ bV,
    short* __restrict__ kp, short* __restrict__ vp)
{
  const int phys = blockIdx.x;
  const int log_ = (phys & 7) * 64 + (phys >> 3);     // 512 = 8*64 bijective
  const int z = log_ >> 8;
  const int rem = log_ & 255;
  const int row0 = (rem >> 1) * 256;
  const int col0 = (rem & 1) * 256;

  const float* X    = (z == 0) ? Kin : Vin;
  const float* bias = (z == 0) ? bK  : bV;
  const short* Wz   = Wt + (size_t)z * 512 * 512;
  short* dst        = (z == 0) ? kp : vp;

  __shared__ short a_lds[2][256 * 32];
  __shared__ short b_lds[2][256 * 32];

  const int tid = threadIdx.x;
  const int lane = tid & 63, wv = tid >> 6;
  const int wr = wv >> 2, wc = wv & 3;                // wave tile: 128 x 64
  const int fr = lane & 15, fg = lane >> 4;

  f32x4 acc[8][4];
#pragma unroll
  for (int i = 0; i < 8; ++i)
#pragma unroll
    for (int j = 0; j < 4; ++j) acc[i][j] = (f32x4){0.f, 0.f, 0.f, 0.f};

  const int ar = tid >> 1;
  const int ak = (tid & 1) * 16;
  const int bl8 = lane * 8;

  { // prologue: tile 0 -> buf 0
#pragma unroll
    for (int i = 0; i < 2; ++i) {
      const int nb = i * 128 + wv * 16;
      gl_lds16(Wz + (size_t)(col0 + nb + (lane >> 2)) * 512 + (lane & 3) * 8,
               &b_lds[0][nb * 32 + bl8]);
    }
    const f32x4* ap = (const f32x4*)(X + (size_t)(row0 + ar) * 512 + ak);
    f32x4 f0 = ap[0], f1 = ap[1], f2 = ap[2], f3 = ap[3];
    uint4v s0, s1;
    s0[0] = pk2(f0[0], f0[1]); s0[1] = pk2(f0[2], f0[3]);
    s0[2] = pk2(f1[0], f1[1]); s0[3] = pk2(f1[2], f1[3]);
    s1[0] = pk2(f2[0], f2[1]); s1[1] = pk2(f2[2], f2[3]);
    s1[2] = pk2(f3[0], f3[1]); s1[3] = pk2(f3[2], f3[3]);
    *(uint4v*)&a_lds[0][ar * 32 + ak] = s0;
    *(uint4v*)&a_lds[0][ar * 32 + ak + 8] = s1;
  }
  __syncthreads();

  for (int t = 0; t < 16; ++t) {
    const int cur = t & 1;
    const bool pf = (t < 15);
    f32x4 p0, p1, p2, p3;
    if (pf) {
      const int k1 = (t + 1) * 32;
      short* bn = b_lds[cur ^ 1];
#pragma unroll
      for (int i = 0; i < 2; ++i) {
        const int nb = i * 128 + wv * 16;
        gl_lds16(Wz + (size_t)(col0 + nb + (lane >> 2)) * 512 + k1 + (lane & 3) * 8,
                 &bn[nb * 32 + bl8]);
      }
      const f32x4* ap = (const f32x4*)(X + (size_t)(row0 + ar) * 512 + k1 + ak);
      p0 = ap[0]; p1 = ap[1]; p2 = ap[2]; p3 = ap[3];
    }

    const short* acur = a_lds[cur];
    const short* bcur = b_lds[cur];
    short8 af[8], bfr[4];
#pragma unroll
    for (int mi = 0; mi < 8; ++mi)
      af[mi] = *(const short8*)&acur[(wr * 128 + mi * 16 + fr) * 32 + fg * 8];
#pragma unroll
    for (int ni = 0; ni < 4; ++ni)
      bfr[ni] = *(const short8*)&bcur[(wc * 64 + ni * 16 + fr) * 32 + fg * 8];
#pragma unroll
    for (int mi = 0; mi < 8; ++mi)
#pragma unroll
      for (int ni = 0; ni < 4; ++ni)
        acc[mi][ni] = __builtin_amdgcn_mfma_f32_16x16x32_bf16(af[mi], bfr[ni], acc[mi][ni], 0, 0, 0);

    if (pf) {
      short* an = a_lds[cur ^ 1];
      uint4v s0, s1;
      s0[0] = pk2(p0[0], p0[1]); s0[1] = pk2(p0[2], p0[3]);
      s0[2] = pk2(p1[0], p1[1]); s0[3] = pk2(p1[2], p1[3]);
      s1[0] = pk2(p2[0], p2[1]); s1[1] = pk2(p2[2], p2[3]);
      s1[2] = pk2(p3[0], p3[1]); s1[3] = pk2(p3[2], p3[3]);
      *(uint4v*)&an[ar * 32 + ak] = s0;
      *(uint4v*)&an[ar * 32 + ak + 8] = s1;
    }
    __syncthreads();
  }

#pragma unroll
  for (int ni = 0; ni < 4; ++ni) {
    const int gc = col0 + wc * 64 + ni * 16 + fr;
    const float bv = bias[gc];
#pragma unroll
    for (int mi = 0; mi < 8; ++mi) {
#pragma unroll
      for (int r = 0; r < 4; ++r) {
        const int gr = row0 + wr * 128 + mi * 16 + fg * 4 + r;
        dst[(size_t)gr * 512 + gc] = f2bf(acc[mi][ni][r] + bv);
      }
    }
  }
}

// ---------------- LN + ktv accumulation (unchanged) -------------------------
#define SC 256
#define TP 264

__global__ __launch_bounds__(256) void ktv_kernel(
    const short* __restrict__ kp, const short* __restrict__ vp,
    const float* __restrict__ pos,
    const float* __restrict__ lnwK, const float* __restrict__ lnbK,
    const float* __restrict__ lnwV, const float* __restrict__ lnbV,
    float* __restrict__ ktv)
{
  const int nh = blockIdx.y;
  const int n = nh >> 4, h = nh & 15;
  const int s0 = blockIdx.x * SC;
  const int tid = threadIdx.x;

  __shared__ short klds[48 * TP];
  __shared__ short vlds[48 * TP];
  __shared__ float lw[2][32], lb[2][32];

  if (tid < 32) {
    lw[0][tid] = lnwK[h * 32 + tid]; lb[0][tid] = lnbK[h * 32 + tid];
    lw[1][tid] = lnwV[h * 32 + tid]; lb[1][tid] = lnbV[h * 32 + tid];
  }
  __syncthreads();

  const size_t rowix = (size_t)n * 8192 + (s0 + tid);
  {
    const short8* src = (const short8*)(kp + rowix * 512 + h * 32);
    short8 r0 = src[0], r1 = src[1], r2 = src[2], r3 = src[3];
    float x[32];
#pragma unroll
    for (int i = 0; i < 8; ++i) { x[i] = bf2f(r0[i]); x[8+i] = bf2f(r1[i]); x[16+i] = bf2f(r2[i]); x[24+i] = bf2f(r3[i]); }
    float mu = 0.f;
#pragma unroll
    for (int i = 0; i < 32; ++i) mu += x[i];
    mu *= (1.f / 32.f);
    float var = 0.f;
#pragma unroll
    for (int i = 0; i < 32; ++i) { float d = x[i] - mu; var += d * d; }
    var *= (1.f / 32.f);
    const float rstd = rsqrtf(var + 1e-5f);
#pragma unroll
    for (int d = 0; d < 32; ++d)
      klds[d * TP + tid] = f2bf((x[d] - mu) * rstd * lw[0][d] + lb[0][d]);
  }
  {
    const short8* src = (const short8*)(vp + rowix * 512 + h * 32);
    short8 r0 = src[0], r1 = src[1], r2 = src[2], r3 = src[3];
    float x[32];
#pragma unroll
    for (int i = 0; i < 8; ++i) { x[i] = bf2f(r0[i]); x[8+i] = bf2f(r1[i]); x[16+i] = bf2f(r2[i]); x[24+i] = bf2f(r3[i]); }
    float mu = 0.f;
#pragma unroll
    for (int i = 0; i < 32; ++i) mu += x[i];
    mu *= (1.f / 32.f);
    float var = 0.f;
#pragma unroll
    for (int i = 0; i < 32; ++i) { float d = x[i] - mu; var += d * d; }
    var *= (1.f / 32.f);
    const float rstd = rsqrtf(var + 1e-5f);
#pragma unroll
    for (int d = 0; d < 32; ++d)
      vlds[d * TP + tid] = f2bf((x[d] - mu) * rstd * lw[1][d] + lb[1][d]);
  }
  {
    const short p0 = f2bf(pos[rowix * 2]);
    const short p1 = f2bf(pos[rowix * 2 + 1]);
    klds[32 * TP + tid] = p0; klds[33 * TP + tid] = p1;
    vlds[32 * TP + tid] = p0; vlds[33 * TP + tid] = p1;
  }
  __syncthreads();

  const int wv = tid >> 6, lane = tid & 63;
  if (wv < 3) {
    const int fr = lane & 15, fg = lane >> 4;
    f32x4 acc[3];
#pragma unroll
    for (int i = 0; i < 3; ++i) acc[i] = (f32x4){0.f, 0.f, 0.f, 0.f};
    for (int kk = 0; kk < SC; kk += 32) {
      short8 a = *(const short8*)&klds[(wv * 16 + fr) * TP + kk + fg * 8];
#pragma unroll
      for (int ni = 0; ni < 3; ++ni) {
        short8 b = *(const short8*)&vlds[(ni * 16 + fr) * TP + kk + fg * 8];
        acc[ni] = __builtin_amdgcn_mfma_f32_16x16x32_bf16(a, b, acc[ni], 0, 0, 0);
      }
    }
#pragma unroll
    for (int ni = 0; ni < 3; ++ni) {
      const int ei = ni * 16 + fr;
      if (ei < 34) {
        const int er = (ei < 32) ? ei + 2 : ei - 32;
#pragma unroll
        for (int r = 0; r < 4; ++r) {
          const int di = wv * 16 + fg * 4 + r;
          if (di < 34) {
            const int dr = (di < 32) ? di + 2 : di - 32;
            atomicAdd(&ktv[((size_t)nh * 34 + dr) * 34 + er], acc[ni][r]);
          }
        }
      }
    }
  }
}

// ---- S-build: St[n][o][h*32+j] = sum_e ktv[n,h,j+2,e]/S * fcW[o][h*34+e] ---
// also atomically accumulates Pp3[n][0/1][o] (pos rows) and Pp3[n][2][o] (bQ@S)
__global__ __launch_bounds__(256) void sbuild_kernel(
    const float* __restrict__ ktv, const float* __restrict__ fcW,
    const float* __restrict__ bQ, float* __restrict__ St, float* __restrict__ Pp3)
{
  const int nh = blockIdx.x;
  const int n = nh >> 4, h = nh & 15;
  __shared__ float g[34 * 34];
  __shared__ float bq[32];
  for (int i = threadIdx.x; i < 34 * 34; i += 256)
    g[i] = ktv[(size_t)nh * 34 * 34 + i] * (1.f / 8192.f);
  if (threadIdx.x < 32) bq[threadIdx.x] = bQ[h * 32 + threadIdx.x];
  __syncthreads();

  for (int o = threadIdx.x; o < 512; o += 256) {
    float wcol[34];
#pragma unroll
    for (int e = 0; e < 34; ++e) wcol[e] = fcW[(size_t)o * 544 + h * 34 + e];
    float p0 = 0.f, p1 = 0.f;
#pragma unroll
    for (int e = 0; e < 34; ++e) { p0 += g[e] * wcol[e]; p1 += g[34 + e] * wcol[e]; }
    float rv = 0.f;
    float* srow = St + ((size_t)n * 512 + o) * 512 + h * 32;
#pragma unroll
    for (int j = 0; j < 32; ++j) {
      float s = 0.f;
#pragma unroll
      for (int e = 0; e < 34; ++e) s += g[(j + 2) * 34 + e] * wcol[e];
      srow[j] = s;
      rv += bq[j] * s;
    }
    atomicAdd(&Pp3[((size_t)n * 3 + 0) * 512 + o], p0);
    atomicAdd(&Pp3[((size_t)n * 3 + 1) * 512 + o], p1);
    atomicAdd(&Pp3[((size_t)n * 3 + 2) * 512 + o], rv);
  }
}

// ---- C-build: Ct[n][o][k] = sum_m St[n][o][m] * WQ[k][m], bf16 out ---------
__global__ __launch_bounds__(256) void cbuild_kernel(
    const float* __restrict__ St, const float* __restrict__ WQ,
    short* __restrict__ Ct)
{
  const int n = blockIdx.z;
  const int row0 = blockIdx.y * 128;   // o
  const int col0 = blockIdx.x * 128;   // k
  const float* A = St + (size_t)n * 512 * 512;
  const float* B = WQ;

  __shared__ short a_lds[128 * 32];
  __shared__ short b_lds[128 * 32];

  const int tid = threadIdx.x;
  const int lane = tid & 63, wv = tid >> 6;
  const int wr = wv >> 1, wc = wv & 1;
  const int fr = lane & 15, fg = lane >> 4;
  const int ar = tid >> 1, ak = (tid & 1) * 16;

  f32x4 acc[4][4];
#pragma unroll
  for (int i = 0; i < 4; ++i)
#pragma unroll
    for (int j = 0; j < 4; ++j) acc[i][j] = (f32x4){0.f, 0.f, 0.f, 0.f};

  for (int k0 = 0; k0 < 512; k0 += 32) {
    __syncthreads();
    {
      const f32x4* ap = (const f32x4*)(A + (size_t)(row0 + ar) * 512 + k0 + ak);
      f32x4 f0 = ap[0], f1 = ap[1], f2 = ap[2], f3 = ap[3];
      uint4v s0, s1;
      s0[0] = pk2(f0[0], f0[1]); s0[1] = pk2(f0[2], f0[3]);
      s0[2] = pk2(f1[0], f1[1]); s0[3] = pk2(f1[2], f1[3]);
      s1[0] = pk2(f2[0], f2[1]); s1[1] = pk2(f2[2], f2[3]);
      s1[2] = pk2(f3[0], f3[1]); s1[3] = pk2(f3[2], f3[3]);
      *(uint4v*)&a_lds[ar * 32 + ak] = s0;
      *(uint4v*)&a_lds[ar * 32 + ak + 8] = s1;
      const f32x4* bp = (const f32x4*)(B + (size_t)(col0 + ar) * 512 + k0 + ak);
      f32x4 g0 = bp[0], g1 = bp[1], g2 = bp[2], g3 = bp[3];
      s0[0] = pk2(g0[0], g0[1]); s0[1] = pk2(g0[2], g0[3]);
      s0[2] = pk2(g1[0], g1[1]); s0[3] = pk2(g1[2], g1[3]);
      s1[0] = pk2(g2[0], g2[1]); s1[1] = pk2(g2[2], g2[3]);
      s1[2] = pk2(g3[0], g3[1]); s1[3] = pk2(g3[2], g3[3]);
      *(uint4v*)&b_lds[ar * 32 + ak] = s0;
      *(uint4v*)&b_lds[ar * 32 + ak + 8] = s1;
    }
    __syncthreads();

    short8 af[4], bfr[4];
#pragma unroll
    for (int mi = 0; mi < 4; ++mi)
      af[mi] = *(const short8*)&a_lds[(wr * 64 + mi * 16 + fr) * 32 + fg * 8];
#pragma unroll
    for (int ni = 0; ni < 4; ++ni)
      bfr[ni] = *(const short8*)&b_lds[(wc * 64 + ni * 16 + fr) * 32 + fg * 8];
#pragma unroll
    for (int mi = 0; mi < 4; ++mi)
#pragma unroll
      for (int ni = 0; ni < 4; ++ni)
        acc[mi][ni] = __builtin_amdgcn_mfma_f32_16x16x32_bf16(af[mi], bfr[ni], acc[mi][ni], 0, 0, 0);
  }

#pragma unroll
  for (int ni = 0; ni < 4; ++ni) {
    const int gc = col0 + wc * 64 + ni * 16 + fr;
#pragma unroll
    for (int mi = 0; mi < 4; ++mi)
#pragma unroll
      for (int r = 0; r < 4; ++r) {
        const int gr = row0 + wr * 64 + mi * 16 + fg * 4 + r;
        Ct[((size_t)n * 512 + gr) * 512 + gc] = f2bf(acc[mi][ni][r]);
      }
  }
}

// ---- fused final GEMM: out[n] = Q[n]@C[n] + pos@Ppos + rv + fc_b -----------
// logical: n (0..3), row0 (0..31)*256, col0 (0..1)*256 -> 256 blocks (1 round)
__global__ __launch_bounds__(512) void fuse_kernel(
    const float* __restrict__ Q, const short* __restrict__ Ct,
    const float* __restrict__ pos, const float* __restrict__ Pp3,
    const float* __restrict__ fcb, float* __restrict__ out)
{
  const int phys = blockIdx.x;
  const int log_ = (phys & 7) * 32 + (phys >> 3);     // 256 = 8*32
  const int n = log_ >> 6;
  const int rem = log_ & 63;
  const int row0 = (rem >> 1) * 256;
  const int col0 = (rem & 1) * 256;

  const float* X = Q + (size_t)n * 8192 * 512;
  const short* B = Ct + (size_t)n * 512 * 512;

  __shared__ short a_lds[2][256 * 32];
  __shared__ short b_lds[2][256 * 32];

  const int tid = threadIdx.x;
  const int lane = tid & 63, wv = tid >> 6;
  const int wr = wv >> 2, wc = wv & 3;
  const int fr = lane & 15, fg = lane >> 4;

  f32x4 acc[8][4];
#pragma unroll
  for (int i = 0; i < 8; ++i)
#pragma unroll
    for (int j = 0; j < 4; ++j) acc[i][j] = (f32x4){0.f, 0.f, 0.f, 0.f};

  const int ar = tid >> 1;
  const int ak = (tid & 1) * 16;
  const int bl8 = lane * 8;

  { // prologue
#pragma unroll
    for (int i = 0; i < 2; ++i) {
      const int nb = i * 128 + wv * 16;
      gl_lds16(B + (size_t)(col0 + nb + (lane >> 2)) * 512 + (lane & 3) * 8,
               &b_lds[0][nb * 32 + bl8]);
    }
    const f32x4* ap = (const f32x4*)(X + (size_t)(row0 + ar) * 512 + ak);
    f32x4 f0 = ap[0], f1 = ap[1], f2 = ap[2], f3 = ap[3];
    uint4v s0, s1;
    s0[0] = pk2(f0[0], f0[1]); s0[1] = pk2(f0[2], f0[3]);
    s0[2] = pk2(f1[0], f1[1]); s0[3] = pk2(f1[2], f1[3]);
    s1[0] = pk2(f2[0], f2[1]); s1[1] = pk2(f2[2], f2[3]);
    s1[2] = pk2(f3[0], f3[1]); s1[3] = pk2(f3[2], f3[3]);
    *(uint4v*)&a_lds[0][ar * 32 + ak] = s0;
    *(uint4v*)&a_lds[0][ar * 32 + ak + 8] = s1;
  }
  __syncthreads();

  for (int t = 0; t < 16; ++t) {
    const int cur = t & 1;
    const bool pf = (t < 15);
    f32x4 p0, p1, p2, p3;
    if (pf) {
      const int k1 = (t + 1) * 32;
      short* bn = b_lds[cur ^ 1];
#pragma unroll
      for (int i = 0; i < 2; ++i) {
        const int nb = i * 128 + wv * 16;
        gl_lds16(B + (size_t)(col0 + nb + (lane >> 2)) * 512 + k1 + (lane & 3) * 8,
                 &bn[nb * 32 + bl8]);
      }
      const f32x4* ap = (const f32x4*)(X + (size_t)(row0 + ar) * 512 + k1 + ak);
      p0 = ap[0]; p1 = ap[1]; p2 = ap[2]; p3 = ap[3];
    }

    const short* acur = a_lds[cur];
    const short* bcur = b_lds[cur];
    short8 af[8], bfr[4];
#pragma unroll
    for (int mi = 0; mi < 8; ++mi)
      af[mi] = *(const short8*)&acur[(wr * 128 + mi * 16 + fr) * 32 + fg * 8];
#pragma unroll
    for (int ni = 0; ni < 4; ++ni)
      bfr[ni] = *(const short8*)&bcur[(wc * 64 + ni * 16 + fr) * 32 + fg * 8];
#pragma unroll
    for (int mi = 0; mi < 8; ++mi)
#pragma unroll
      for (int ni = 0; ni < 4; ++ni)
        acc[mi][ni] = __builtin_amdgcn_mfma_f32_16x16x32_bf16(af[mi], bfr[ni], acc[mi][ni], 0, 0, 0);

    if (pf) {
      short* an = a_lds[cur ^ 1];
      uint4v s0, s1;
      s0[0] = pk2(p0[0], p0[1]); s0[1] = pk2(p0[2], p0[3]);
      s0[2] = pk2(p1[0], p1[1]); s0[3] = pk2(p1[2], p1[3]);
      s1[0] = pk2(p2[0], p2[1]); s1[1] = pk2(p2[2], p2[3]);
      s1[2] = pk2(p3[0], p3[1]); s1[3] = pk2(p3[2], p3[3]);
      *(uint4v*)&an[ar * 32 + ak] = s0;
      *(uint4v*)&an[ar * 32 + ak + 8] = s1;
    }
    __syncthreads();
  }

  // epilogue: + pos-term + bQ-term + fc_b
  float pp0[4], pp1[4], rv[4];
#pragma unroll
  for (int ni = 0; ni < 4; ++ni) {
    const int gc = col0 + wc * 64 + ni * 16 + fr;
    pp0[ni] = Pp3[((size_t)n * 3 + 0) * 512 + gc];
    pp1[ni] = Pp3[((size_t)n * 3 + 1) * 512 + gc];
    rv[ni]  = Pp3[((size_t)n * 3 + 2) * 512 + gc] + fcb[gc];
  }
#pragma unroll
  for (int mi = 0; mi < 8; ++mi) {
#pragma unroll
    for (int r = 0; r < 4; ++r) {
      const int gr = row0 + wr * 128 + mi * 16 + fg * 4 + r;
      const float* pr = pos + ((size_t)n * 8192 + gr) * 2;
      const float q0 = pr[0], q1 = pr[1];
#pragma unroll
      for (int ni = 0; ni < 4; ++ni) {
        const int gc = col0 + wc * 64 + ni * 16 + fr;
        out[((size_t)n * 8192 + gr) * 512 + gc] =
            acc[mi][ni][r] + pp0[ni] * q0 + pp1[ni] * q1 + rv[ni];
      }
    }
  }
}

// ---------------------------------------------------------------------------
extern "C" void kernel_launch(void* const* d_in, const int* in_sizes, int n_in,
                              void* d_out, int out_size, void* d_ws, size_t ws_size,
                              hipStream_t stream) {
  const float* Q    = (const float*)d_in[0];
  const float* Kin  = (const float*)d_in[1];
  const float* Vin  = (const float*)d_in[2];
  const float* pos  = (const float*)d_in[3];
  const float* WQ   = (const float*)d_in[4];
  const float* WK   = (const float*)d_in[5];
  const float* WV   = (const float*)d_in[6];
  const float* bQ   = (const float*)d_in[7];
  const float* bK   = (const float*)d_in[8];
  const float* bV   = (const float*)d_in[9];
  const float* lnwK = (const float*)d_in[10];
  const float* lnbK = (const float*)d_in[11];
  const float* lnwV = (const float*)d_in[12];
  const float* lnbV = (const float*)d_in[13];
  const float* fcW  = (const float*)d_in[14];
  const float* fcb  = (const float*)d_in[15];

  char* ws = (char*)d_ws;
  const size_t KP_B  = (size_t)4 * 8192 * 512 * 2;   // 33,554,432
  const size_t KTV_B = (size_t)64 * 34 * 34 * 4;     //    295,936
  const size_t ST_B  = (size_t)4 * 512 * 512 * 4;    //  4,194,304
  const size_t CT_B  = (size_t)4 * 512 * 512 * 2;    //  2,097,152
  const size_t WT_B  = (size_t)2 * 512 * 512 * 2;    //  1,048,576
  const size_t PP_B  = (size_t)4 * 3 * 512 * 4;      //     24,576
  short* kp  = (short*)ws;
  short* vp  = (short*)(ws + KP_B);
  float* ktv = (float*)(ws + 2 * KP_B);
  float* St  = (float*)(ws + 2 * KP_B + KTV_B);
  short* Ct  = (short*)(ws + 2 * KP_B + KTV_B + ST_B);
  short* Wt  = (short*)(ws + 2 * KP_B + KTV_B + ST_B + CT_B);
  float* Pp3 = (float*)(ws + 2 * KP_B + KTV_B + ST_B + CT_B + WT_B);

  (void)hipMemsetAsync(ktv, 0, KTV_B, stream);
  (void)hipMemsetAsync(Pp3, 0, PP_B, stream);
  hipLaunchKernelGGL(wt_kernel, dim3(8, 8, 2), dim3(256), 0, stream, WK, WV, Wt);
  hipLaunchKernelGGL(proj_kernel, dim3(512), dim3(512), 0, stream,
                     Kin, Vin, Wt, bK, bV, kp, vp);
  hipLaunchKernelGGL(ktv_kernel, dim3(32, 64), dim3(256), 0, stream,
                     kp, vp, pos, lnwK, lnbK, lnwV, lnbV, ktv);
  hipLaunchKernelGGL(sbuild_kernel, dim3(64), dim3(256), 0, stream,
                     ktv, fcW, bQ, St, Pp3);
  hipLaunchKernelGGL(cbuild_kernel, dim3(4, 4, 4), dim3(256), 0, stream,
                     St, WQ, Ct);
  hipLaunchKernelGGL(fuse_kernel, dim3(256), dim3(512), 0, stream,
                     Q, Ct, pos, Pp3, fcb, (float*)d_out);
}

// Round 7
// 223.428 us; speedup vs baseline: 1.1433x; 1.0372x over previous
//
#include <hip/hip_runtime.h>
#include <hip/hip_bf16.h>

typedef short short8 __attribute__((ext_vector_type(8)));
typedef float f32x4 __attribute__((ext_vector_type(4)));
typedef unsigned int uint4v __attribute__((ext_vector_type(4)));

__device__ __forceinline__ short f2bf(float f) {
  unsigned u = __builtin_bit_cast(unsigned, f);
  u += 0x7fffu + ((u >> 16) & 1u);          // RNE
  return (short)(u >> 16);
}
__device__ __forceinline__ float bf2f(short s) {
  unsigned u = ((unsigned)(unsigned short)s) << 16;
  return __builtin_bit_cast(float, u);
}
__device__ __forceinline__ unsigned pk2(float a, float b) {
  __hip_bfloat162 h = __float22bfloat162_rn(float2{a, b});
  unsigned u;
  __builtin_memcpy(&u, &h, 4);
  return u;
}
__device__ __forceinline__ void gl_lds16(const void* g, void* l) {
  __builtin_amdgcn_global_load_lds(
      (const __attribute__((address_space(1))) unsigned int*)g,
      (__attribute__((address_space(3))) unsigned int*)l, 16, 0, 0);
}

// ---------------- W transpose + bf16: Wt[z][n][k], z=0:WK z=1:WV ------------
__global__ __launch_bounds__(256) void wt_kernel(
    const float* __restrict__ WK, const float* __restrict__ WV,
    short* __restrict__ Wt)
{
  const int z = blockIdx.z;
  const float* W = (z == 0) ? WK : WV;
  short* o = Wt + (size_t)z * 512 * 512;
  __shared__ short t[64][65];
  const int k0 = blockIdx.y * 64, n0 = blockIdx.x * 64;
  const int c = threadIdx.x & 63, rb = threadIdx.x >> 6;
#pragma unroll
  for (int p = 0; p < 16; ++p) {
    const int kk = p * 4 + rb;
    t[kk][c] = f2bf(W[(size_t)(k0 + kk) * 512 + n0 + c]);
  }
  __syncthreads();
#pragma unroll
  for (int p = 0; p < 16; ++p) {
    const int nn = p * 4 + rb;
    o[(size_t)(n0 + nn) * 512 + k0 + c] = t[c][nn];
  }
}

// ======== 256x256 / BK=64 counted-vmcnt pipelined GEMM body (proj) ==========
// K/V projection: logical z (0..1), row0 (0..127)*256, col0 (0..1)*256
__global__ __launch_bounds__(512, 2) void proj_kernel(
    const float* __restrict__ Kin, const float* __restrict__ Vin,
    const short* __restrict__ Wt,
    const float* __restrict__ bK, const float* __restrict__ bV,
    short* __restrict__ kp, short* __restrict__ vp)
{
  const int phys = blockIdx.x;
  const int log_ = (phys & 7) * 64 + (phys >> 3);     // 512 = 8*64 bijective
  const int z = log_ >> 8;
  const int rem = log_ & 255;
  const int row0 = (rem >> 1) * 256;
  const int col0 = (rem & 1) * 256;

  const float* X    = (z == 0) ? Kin : Vin;
  const float* bias = (z == 0) ? bK  : bV;
  const short* Wz   = Wt + (size_t)z * 512 * 512;
  short* dst        = (z == 0) ? kp : vp;

  __shared__ short a_lds[2][256 * 64];
  __shared__ short b_lds[2][256 * 64];

  const int tid = threadIdx.x;
  const int lane = tid & 63, wv = tid >> 6;
  const int wr = wv >> 2, wc = wv & 3;                // wave tile 128x64
  const int fr = lane & 15, fg = lane >> 4;
  const int sx = fr & 7;

  // A staging: thread -> row (0..255), 32-float segment
  const int arow = tid >> 1, aseg = tid & 1;
  const float* abase = X + (size_t)(row0 + arow) * 512 + aseg * 32;
  int awoff[4];
#pragma unroll
  for (int m = 0; m < 4; ++m)
    awoff[m] = arow * 64 + (((aseg * 4 + m) ^ (arow & 7)) * 8);

  // B staging: wave wv covers rows wv*32+i*8+(lane>>3); slot lane&7, XOR'd source
  const int brbase = col0 + wv * 32 + (lane >> 3);
  const int bxor = ((lane & 7) ^ (lane >> 3)) * 8;
  const int bldsbase = (wv * 32) * 64;

  f32x4 acc[8][4];
#pragma unroll
  for (int i = 0; i < 8; ++i)
#pragma unroll
    for (int j = 0; j < 4; ++j) acc[i][j] = (f32x4){0.f, 0.f, 0.f, 0.f};

  f32x4 pA[8];

  { // prologue: tile 0
#pragma unroll
    for (int j = 0; j < 8; ++j) pA[j] = *(const f32x4*)(abase + j * 4);
#pragma unroll
    for (int i = 0; i < 4; ++i)
      gl_lds16(Wz + (size_t)(brbase + i * 8) * 512 + bxor,
               &b_lds[0][bldsbase + i * 8 * 64]);
#pragma unroll
    for (int m = 0; m < 4; ++m) {
      uint4v s;
      s[0] = pk2(pA[2*m][0], pA[2*m][1]);     s[1] = pk2(pA[2*m][2], pA[2*m][3]);
      s[2] = pk2(pA[2*m+1][0], pA[2*m+1][1]); s[3] = pk2(pA[2*m+1][2], pA[2*m+1][3]);
      *(uint4v*)&a_lds[0][awoff[m]] = s;
    }
  }

  for (int t = 0; t < 8; ++t) {
    if (t < 7) {
      const float* ap = abase + (t + 1) * 64;
#pragma unroll
      for (int j = 0; j < 8; ++j) pA[j] = *(const f32x4*)(ap + j * 4);
      asm volatile("s_waitcnt vmcnt(8) lgkmcnt(0)" ::: "memory");
    } else {
      asm volatile("s_waitcnt vmcnt(0) lgkmcnt(0)" ::: "memory");
    }
    __builtin_amdgcn_s_barrier();
    __builtin_amdgcn_sched_barrier(0);
    if (t < 7) {
      short* bn = &b_lds[(t + 1) & 1][0];
      const int k1 = (t + 1) * 64;
#pragma unroll
      for (int i = 0; i < 4; ++i)
        gl_lds16(Wz + (size_t)(brbase + i * 8) * 512 + k1 + bxor,
                 bn + bldsbase + i * 8 * 64);
    }
    const short* ac = &a_lds[t & 1][0];
    const short* bc = &b_lds[t & 1][0];
#pragma unroll
    for (int kk = 0; kk < 2; ++kk) {
      const int so = ((kk * 4 + fg) ^ sx) * 8;
      short8 af[8], bfv[4];
#pragma unroll
      for (int ni = 0; ni < 4; ++ni)
        bfv[ni] = *(const short8*)&bc[(wc * 64 + ni * 16 + fr) * 64 + so];
#pragma unroll
      for (int mi = 0; mi < 8; ++mi)
        af[mi] = *(const short8*)&ac[(wr * 128 + mi * 16 + fr) * 64 + so];
      __builtin_amdgcn_s_setprio(1);
#pragma unroll
      for (int mi = 0; mi < 8; ++mi)
#pragma unroll
        for (int ni = 0; ni < 4; ++ni)
          acc[mi][ni] = __builtin_amdgcn_mfma_f32_16x16x32_bf16(af[mi], bfv[ni], acc[mi][ni], 0, 0, 0);
      __builtin_amdgcn_s_setprio(0);
    }
    if (t < 7) {
      short* an = &a_lds[(t + 1) & 1][0];
#pragma unroll
      for (int m = 0; m < 4; ++m) {
        uint4v s;
        s[0] = pk2(pA[2*m][0], pA[2*m][1]);     s[1] = pk2(pA[2*m][2], pA[2*m][3]);
        s[2] = pk2(pA[2*m+1][0], pA[2*m+1][1]); s[3] = pk2(pA[2*m+1][2], pA[2*m+1][3]);
        *(uint4v*)&an[awoff[m]] = s;
      }
    }
  }

#pragma unroll
  for (int ni = 0; ni < 4; ++ni) {
    const int gc = col0 + wc * 64 + ni * 16 + fr;
    const float bv = bias[gc];
#pragma unroll
    for (int mi = 0; mi < 8; ++mi) {
#pragma unroll
      for (int r = 0; r < 4; ++r) {
        const int gr = row0 + wr * 128 + mi * 16 + fg * 4 + r;
        dst[(size_t)gr * 512 + gc] = f2bf(acc[mi][ni][r] + bv);
      }
    }
  }
}

// ---------------- LN + ktv accumulation (unchanged) -------------------------
#define SC 256
#define TP 264

__global__ __launch_bounds__(256) void ktv_kernel(
    const short* __restrict__ kp, const short* __restrict__ vp,
    const float* __restrict__ pos,
    const float* __restrict__ lnwK, const float* __restrict__ lnbK,
    const float* __restrict__ lnwV, const float* __restrict__ lnbV,
    float* __restrict__ ktv)
{
  const int nh = blockIdx.y;
  const int n = nh >> 4, h = nh & 15;
  const int s0 = blockIdx.x * SC;
  const int tid = threadIdx.x;

  __shared__ short klds[48 * TP];
  __shared__ short vlds[48 * TP];
  __shared__ float lw[2][32], lb[2][32];

  if (tid < 32) {
    lw[0][tid] = lnwK[h * 32 + tid]; lb[0][tid] = lnbK[h * 32 + tid];
    lw[1][tid] = lnwV[h * 32 + tid]; lb[1][tid] = lnbV[h * 32 + tid];
  }
  __syncthreads();

  const size_t rowix = (size_t)n * 8192 + (s0 + tid);
  {
    const short8* src = (const short8*)(kp + rowix * 512 + h * 32);
    short8 r0 = src[0], r1 = src[1], r2 = src[2], r3 = src[3];
    float x[32];
#pragma unroll
    for (int i = 0; i < 8; ++i) { x[i] = bf2f(r0[i]); x[8+i] = bf2f(r1[i]); x[16+i] = bf2f(r2[i]); x[24+i] = bf2f(r3[i]); }
    float mu = 0.f;
#pragma unroll
    for (int i = 0; i < 32; ++i) mu += x[i];
    mu *= (1.f / 32.f);
    float var = 0.f;
#pragma unroll
    for (int i = 0; i < 32; ++i) { float d = x[i] - mu; var += d * d; }
    var *= (1.f / 32.f);
    const float rstd = rsqrtf(var + 1e-5f);
#pragma unroll
    for (int d = 0; d < 32; ++d)
      klds[d * TP + tid] = f2bf((x[d] - mu) * rstd * lw[0][d] + lb[0][d]);
  }
  {
    const short8* src = (const short8*)(vp + rowix * 512 + h * 32);
    short8 r0 = src[0], r1 = src[1], r2 = src[2], r3 = src[3];
    float x[32];
#pragma unroll
    for (int i = 0; i < 8; ++i) { x[i] = bf2f(r0[i]); x[8+i] = bf2f(r1[i]); x[16+i] = bf2f(r2[i]); x[24+i] = bf2f(r3[i]); }
    float mu = 0.f;
#pragma unroll
    for (int i = 0; i < 32; ++i) mu += x[i];
    mu *= (1.f / 32.f);
    float var = 0.f;
#pragma unroll
    for (int i = 0; i < 32; ++i) { float d = x[i] - mu; var += d * d; }
    var *= (1.f / 32.f);
    const float rstd = rsqrtf(var + 1e-5f);
#pragma unroll
    for (int d = 0; d < 32; ++d)
      vlds[d * TP + tid] = f2bf((x[d] - mu) * rstd * lw[1][d] + lb[1][d]);
  }
  {
    const short p0 = f2bf(pos[rowix * 2]);
    const short p1 = f2bf(pos[rowix * 2 + 1]);
    klds[32 * TP + tid] = p0; klds[33 * TP + tid] = p1;
    vlds[32 * TP + tid] = p0; vlds[33 * TP + tid] = p1;
  }
  __syncthreads();

  const int wv = tid >> 6, lane = tid & 63;
  if (wv < 3) {
    const int fr = lane & 15, fg = lane >> 4;
    f32x4 acc[3];
#pragma unroll
    for (int i = 0; i < 3; ++i) acc[i] = (f32x4){0.f, 0.f, 0.f, 0.f};
    for (int kk = 0; kk < SC; kk += 32) {
      short8 a = *(const short8*)&klds[(wv * 16 + fr) * TP + kk + fg * 8];
#pragma unroll
      for (int ni = 0; ni < 3; ++ni) {
        short8 b = *(const short8*)&vlds[(ni * 16 + fr) * TP + kk + fg * 8];
        acc[ni] = __builtin_amdgcn_mfma_f32_16x16x32_bf16(a, b, acc[ni], 0, 0, 0);
      }
    }
#pragma unroll
    for (int ni = 0; ni < 3; ++ni) {
      const int ei = ni * 16 + fr;
      if (ei < 34) {
        const int er = (ei < 32) ? ei + 2 : ei - 32;
#pragma unroll
        for (int r = 0; r < 4; ++r) {
          const int di = wv * 16 + fg * 4 + r;
          if (di < 34) {
            const int dr = (di < 32) ? di + 2 : di - 32;
            atomicAdd(&ktv[((size_t)nh * 34 + dr) * 34 + er], acc[ni][r]);
          }
        }
      }
    }
  }
}

// ---- S-build: St[n][o][h*32+j] = sum_e ktv[n,h,j+2,e]/S * fcW[o][h*34+e] ---
__global__ __launch_bounds__(256) void sbuild_kernel(
    const float* __restrict__ ktv, const float* __restrict__ fcW,
    const float* __restrict__ bQ, float* __restrict__ St, float* __restrict__ Pp3)
{
  const int nh = blockIdx.x;
  const int n = nh >> 4, h = nh & 15;
  __shared__ float g[34 * 34];
  __shared__ float bq[32];
  for (int i = threadIdx.x; i < 34 * 34; i += 256)
    g[i] = ktv[(size_t)nh * 34 * 34 + i] * (1.f / 8192.f);
  if (threadIdx.x < 32) bq[threadIdx.x] = bQ[h * 32 + threadIdx.x];
  __syncthreads();

  for (int o = threadIdx.x; o < 512; o += 256) {
    float wcol[34];
#pragma unroll
    for (int e = 0; e < 34; ++e) wcol[e] = fcW[(size_t)o * 544 + h * 34 + e];
    float p0 = 0.f, p1 = 0.f;
#pragma unroll
    for (int e = 0; e < 34; ++e) { p0 += g[e] * wcol[e]; p1 += g[34 + e] * wcol[e]; }
    float rv = 0.f;
    float* srow = St + ((size_t)n * 512 + o) * 512 + h * 32;
#pragma unroll
    for (int j = 0; j < 32; ++j) {
      float s = 0.f;
#pragma unroll
      for (int e = 0; e < 34; ++e) s += g[(j + 2) * 34 + e] * wcol[e];
      srow[j] = s;
      rv += bq[j] * s;
    }
    atomicAdd(&Pp3[((size_t)n * 3 + 0) * 512 + o], p0);
    atomicAdd(&Pp3[((size_t)n * 3 + 1) * 512 + o], p1);
    atomicAdd(&Pp3[((size_t)n * 3 + 2) * 512 + o], rv);
  }
}

// ---- C-build: Ct[n][o][k] = sum_m St[n][o][m] * WQ[k][m], bf16 out ---------
__global__ __launch_bounds__(256) void cbuild_kernel(
    const float* __restrict__ St, const float* __restrict__ WQ,
    short* __restrict__ Ct)
{
  const int n = blockIdx.z;
  const int row0 = blockIdx.y * 128;   // o
  const int col0 = blockIdx.x * 128;   // k
  const float* A = St + (size_t)n * 512 * 512;
  const float* B = WQ;

  __shared__ short a_lds[128 * 32];
  __shared__ short b_lds[128 * 32];

  const int tid = threadIdx.x;
  const int lane = tid & 63, wv = tid >> 6;
  const int wr = wv >> 1, wc = wv & 1;
  const int fr = lane & 15, fg = lane >> 4;
  const int ar = tid >> 1, ak = (tid & 1) * 16;

  f32x4 acc[4][4];
#pragma unroll
  for (int i = 0; i < 4; ++i)
#pragma unroll
    for (int j = 0; j < 4; ++j) acc[i][j] = (f32x4){0.f, 0.f, 0.f, 0.f};

  for (int k0 = 0; k0 < 512; k0 += 32) {
    __syncthreads();
    {
      const f32x4* ap = (const f32x4*)(A + (size_t)(row0 + ar) * 512 + k0 + ak);
      f32x4 f0 = ap[0], f1 = ap[1], f2 = ap[2], f3 = ap[3];
      uint4v s0, s1;
      s0[0] = pk2(f0[0], f0[1]); s0[1] = pk2(f0[2], f0[3]);
      s0[2] = pk2(f1[0], f1[1]); s0[3] = pk2(f1[2], f1[3]);
      s1[0] = pk2(f2[0], f2[1]); s1[1] = pk2(f2[2], f2[3]);
      s1[2] = pk2(f3[0], f3[1]); s1[3] = pk2(f3[2], f3[3]);
      *(uint4v*)&a_lds[ar * 32 + ak] = s0;
      *(uint4v*)&a_lds[ar * 32 + ak + 8] = s1;
      const f32x4* bp = (const f32x4*)(B + (size_t)(col0 + ar) * 512 + k0 + ak);
      f32x4 g0 = bp[0], g1 = bp[1], g2 = bp[2], g3 = bp[3];
      s0[0] = pk2(g0[0], g0[1]); s0[1] = pk2(g0[2], g0[3]);
      s0[2] = pk2(g1[0], g1[1]); s0[3] = pk2(g1[2], g1[3]);
      s1[0] = pk2(g2[0], g2[1]); s1[1] = pk2(g2[2], g2[3]);
      s1[2] = pk2(g3[0], g3[1]); s1[3] = pk2(g3[2], g3[3]);
      *(uint4v*)&b_lds[ar * 32 + ak] = s0;
      *(uint4v*)&b_lds[ar * 32 + ak + 8] = s1;
    }
    __syncthreads();

    short8 af[4], bfr[4];
#pragma unroll
    for (int mi = 0; mi < 4; ++mi)
      af[mi] = *(const short8*)&a_lds[(wr * 64 + mi * 16 + fr) * 32 + fg * 8];
#pragma unroll
    for (int ni = 0; ni < 4; ++ni)
      bfr[ni] = *(const short8*)&b_lds[(wc * 64 + ni * 16 + fr) * 32 + fg * 8];
#pragma unroll
    for (int mi = 0; mi < 4; ++mi)
#pragma unroll
      for (int ni = 0; ni < 4; ++ni)
        acc[mi][ni] = __builtin_amdgcn_mfma_f32_16x16x32_bf16(af[mi], bfr[ni], acc[mi][ni], 0, 0, 0);
  }

#pragma unroll
  for (int ni = 0; ni < 4; ++ni) {
    const int gc = col0 + wc * 64 + ni * 16 + fr;
#pragma unroll
    for (int mi = 0; mi < 4; ++mi)
#pragma unroll
      for (int r = 0; r < 4; ++r) {
        const int gr = row0 + wr * 64 + mi * 16 + fg * 4 + r;
        Ct[((size_t)n * 512 + gr) * 512 + gc] = f2bf(acc[mi][ni][r]);
      }
  }
}

// ---- fused final GEMM: out[n] = Q[n]@C[n] + pos@Ppos + rv + fc_b -----------
// counted-vmcnt pipeline; logical: n(0..3), row0(0..31)*256, col0(0..1)*256
__global__ __launch_bounds__(512, 2) void fuse_kernel(
    const float* __restrict__ Q, const short* __restrict__ Ct,
    const float* __restrict__ pos, const float* __restrict__ Pp3,
    const float* __restrict__ fcb, float* __restrict__ out)
{
  const int phys = blockIdx.x;
  const int log_ = (phys & 7) * 32 + (phys >> 3);     // 256 = 8*32
  const int n = log_ >> 6;
  const int rem = log_ & 63;
  const int row0 = (rem >> 1) * 256;
  const int col0 = (rem & 1) * 256;

  const float* X = Q + (size_t)n * 8192 * 512;
  const short* Bz = Ct + (size_t)n * 512 * 512;

  __shared__ short a_lds[2][256 * 64];
  __shared__ short b_lds[2][256 * 64];

  const int tid = threadIdx.x;
  const int lane = tid & 63, wv = tid >> 6;
  const int wr = wv >> 2, wc = wv & 3;
  const int fr = lane & 15, fg = lane >> 4;
  const int sx = fr & 7;

  const int arow = tid >> 1, aseg = tid & 1;
  const float* abase = X + (size_t)(row0 + arow) * 512 + aseg * 32;
  int awoff[4];
#pragma unroll
  for (int m = 0; m < 4; ++m)
    awoff[m] = arow * 64 + (((aseg * 4 + m) ^ (arow & 7)) * 8);

  const int brbase = col0 + wv * 32 + (lane >> 3);
  const int bxor = ((lane & 7) ^ (lane >> 3)) * 8;
  const int bldsbase = (wv * 32) * 64;

  f32x4 acc[8][4];
#pragma unroll
  for (int i = 0; i < 8; ++i)
#pragma unroll
    for (int j = 0; j < 4; ++j) acc[i][j] = (f32x4){0.f, 0.f, 0.f, 0.f};

  f32x4 pA[8];

  { // prologue
#pragma unroll
    for (int j = 0; j < 8; ++j) pA[j] = *(const f32x4*)(abase + j * 4);
#pragma unroll
    for (int i = 0; i < 4; ++i)
      gl_lds16(Bz + (size_t)(brbase + i * 8) * 512 + bxor,
               &b_lds[0][bldsbase + i * 8 * 64]);
#pragma unroll
    for (int m = 0; m < 4; ++m) {
      uint4v s;
      s[0] = pk2(pA[2*m][0], pA[2*m][1]);     s[1] = pk2(pA[2*m][2], pA[2*m][3]);
      s[2] = pk2(pA[2*m+1][0], pA[2*m+1][1]); s[3] = pk2(pA[2*m+1][2], pA[2*m+1][3]);
      *(uint4v*)&a_lds[0][awoff[m]] = s;
    }
  }

  for (int t = 0; t < 8; ++t) {
    if (t < 7) {
      const float* ap = abase + (t + 1) * 64;
#pragma unroll
      for (int j = 0; j < 8; ++j) pA[j] = *(const f32x4*)(ap + j * 4);
      asm volatile("s_waitcnt vmcnt(8) lgkmcnt(0)" ::: "memory");
    } else {
      asm volatile("s_waitcnt vmcnt(0) lgkmcnt(0)" ::: "memory");
    }
    __builtin_amdgcn_s_barrier();
    __builtin_amdgcn_sched_barrier(0);
    if (t < 7) {
      short* bn = &b_lds[(t + 1) & 1][0];
      const int k1 = (t + 1) * 64;
#pragma unroll
      for (int i = 0; i < 4; ++i)
        gl_lds16(Bz + (size_t)(brbase + i * 8) * 512 + k1 + bxor,
                 bn + bldsbase + i * 8 * 64);
    }
    const short* ac = &a_lds[t & 1][0];
    const short* bc = &b_lds[t & 1][0];
#pragma unroll
    for (int kk = 0; kk < 2; ++kk) {
      const int so = ((kk * 4 + fg) ^ sx) * 8;
      short8 af[8], bfv[4];
#pragma unroll
      for (int ni = 0; ni < 4; ++ni)
        bfv[ni] = *(const short8*)&bc[(wc * 64 + ni * 16 + fr) * 64 + so];
#pragma unroll
      for (int mi = 0; mi < 8; ++mi)
        af[mi] = *(const short8*)&ac[(wr * 128 + mi * 16 + fr) * 64 + so];
      __builtin_amdgcn_s_setprio(1);
#pragma unroll
      for (int mi = 0; mi < 8; ++mi)
#pragma unroll
        for (int ni = 0; ni < 4; ++ni)
          acc[mi][ni] = __builtin_amdgcn_mfma_f32_16x16x32_bf16(af[mi], bfv[ni], acc[mi][ni], 0, 0, 0);
      __builtin_amdgcn_s_setprio(0);
    }
    if (t < 7) {
      short* an = &a_lds[(t + 1) & 1][0];
#pragma unroll
      for (int m = 0; m < 4; ++m) {
        uint4v s;
        s[0] = pk2(pA[2*m][0], pA[2*m][1]);     s[1] = pk2(pA[2*m][2], pA[2*m][3]);
        s[2] = pk2(pA[2*m+1][0], pA[2*m+1][1]); s[3] = pk2(pA[2*m+1][2], pA[2*m+1][3]);
        *(uint4v*)&an[awoff[m]] = s;
      }
    }
  }

  // epilogue: + pos-term + bQ-term + fc_b
  float pp0[4], pp1[4], rv[4];
#pragma unroll
  for (int ni = 0; ni < 4; ++ni) {
    const int gc = col0 + wc * 64 + ni * 16 + fr;
    pp0[ni] = Pp3[((size_t)n * 3 + 0) * 512 + gc];
    pp1[ni] = Pp3[((size_t)n * 3 + 1) * 512 + gc];
    rv[ni]  = Pp3[((size_t)n * 3 + 2) * 512 + gc] + fcb[gc];
  }
#pragma unroll
  for (int mi = 0; mi < 8; ++mi) {
#pragma unroll
    for (int r = 0; r < 4; ++r) {
      const int gr = row0 + wr * 128 + mi * 16 + fg * 4 + r;
      const float* pr = pos + ((size_t)n * 8192 + gr) * 2;
      const float q0 = pr[0], q1 = pr[1];
#pragma unroll
      for (int ni = 0; ni < 4; ++ni) {
        const int gc = col0 + wc * 64 + ni * 16 + fr;
        out[((size_t)n * 8192 + gr) * 512 + gc] =
            acc[mi][ni][r] + pp0[ni] * q0 + pp1[ni] * q1 + rv[ni];
      }
    }
  }
}

// ---------------------------------------------------------------------------
extern "C" void kernel_launch(void* const* d_in, const int* in_sizes, int n_in,
                              void* d_out, int out_size, void* d_ws, size_t ws_size,
                              hipStream_t stream) {
  const float* Q    = (const float*)d_in[0];
  const float* Kin  = (const float*)d_in[1];
  const float* Vin  = (const float*)d_in[2];
  const float* pos  = (const float*)d_in[3];
  const float* WQ   = (const float*)d_in[4];
  const float* WK   = (const float*)d_in[5];
  const float* WV   = (const float*)d_in[6];
  const float* bQ   = (const float*)d_in[7];
  const float* bK   = (const float*)d_in[8];
  const float* bV   = (const float*)d_in[9];
  const float* lnwK = (const float*)d_in[10];
  const float* lnbK = (const float*)d_in[11];
  const float* lnwV = (const float*)d_in[12];
  const float* lnbV = (const float*)d_in[13];
  const float* fcW  = (const float*)d_in[14];
  const float* fcb  = (const float*)d_in[15];

  char* ws = (char*)d_ws;
  const size_t KP_B  = (size_t)4 * 8192 * 512 * 2;   // 33,554,432
  const size_t KTV_B = (size_t)64 * 34 * 34 * 4;     //    295,936
  const size_t ST_B  = (size_t)4 * 512 * 512 * 4;    //  4,194,304
  const size_t CT_B  = (size_t)4 * 512 * 512 * 2;    //  2,097,152
  const size_t WT_B  = (size_t)2 * 512 * 512 * 2;    //  1,048,576
  const size_t PP_B  = (size_t)4 * 3 * 512 * 4;      //     24,576
  short* kp  = (short*)ws;
  short* vp  = (short*)(ws + KP_B);
  float* ktv = (float*)(ws + 2 * KP_B);
  float* St  = (float*)(ws + 2 * KP_B + KTV_B);
  short* Ct  = (short*)(ws + 2 * KP_B + KTV_B + ST_B);
  short* Wt  = (short*)(ws + 2 * KP_B + KTV_B + ST_B + CT_B);
  float* Pp3 = (float*)(ws + 2 * KP_B + KTV_B + ST_B + CT_B + WT_B);

  (void)hipMemsetAsync(ktv, 0, KTV_B, stream);
  (void)hipMemsetAsync(Pp3, 0, PP_B, stream);
  hipLaunchKernelGGL(wt_kernel, dim3(8, 8, 2), dim3(256), 0, stream, WK, WV, Wt);
  hipLaunchKernelGGL(proj_kernel, dim3(512), dim3(512), 0, stream,
                     Kin, Vin, Wt, bK, bV, kp, vp);
  hipLaunchKernelGGL(ktv_kernel, dim3(32, 64), dim3(256), 0, stream,
                     kp, vp, pos, lnwK, lnbK, lnwV, lnbV, ktv);
  hipLaunchKernelGGL(sbuild_kernel, dim3(64), dim3(256), 0, stream,
                     ktv, fcW, bQ, St, Pp3);
  hipLaunchKernelGGL(cbuild_kernel, dim3(4, 4, 4), dim3(256), 0, stream,
                     St, WQ, Ct);
  hipLaunchKernelGGL(fuse_kernel, dim3(256), dim3(512), 0, stream,
                     Q, Ct, pos, Pp3, fcb, (float*)d_out);
}

// Round 8
// 200.233 us; speedup vs baseline: 1.2757x; 1.1158x over previous
//
#include <hip/hip_runtime.h>
#include <hip/hip_bf16.h>

typedef short short8 __attribute__((ext_vector_type(8)));
typedef float f32x4 __attribute__((ext_vector_type(4)));
typedef unsigned int uint4v __attribute__((ext_vector_type(4)));

__device__ __forceinline__ short f2bf(float f) {
  unsigned u = __builtin_bit_cast(unsigned, f);
  u += 0x7fffu + ((u >> 16) & 1u);          // RNE
  return (short)(u >> 16);
}
__device__ __forceinline__ float bf2f(short s) {
  unsigned u = ((unsigned)(unsigned short)s) << 16;
  return __builtin_bit_cast(float, u);
}
__device__ __forceinline__ unsigned pk2(float a, float b) {
  __hip_bfloat162 h = __float22bfloat162_rn(float2{a, b});
  unsigned u;
  __builtin_memcpy(&u, &h, 4);
  return u;
}
__device__ __forceinline__ void gl_lds16(const void* g, void* l) {
  __builtin_amdgcn_global_load_lds(
      (const __attribute__((address_space(1))) unsigned int*)g,
      (__attribute__((address_space(3))) unsigned int*)l, 16, 0, 0);
}
// 16 fp32 (4x f32x4) -> 2x 16B bf16 LDS writes
__device__ __forceinline__ void cvt16(const f32x4* p, short* d0, short* d1) {
  uint4v s;
  s[0] = pk2(p[0][0], p[0][1]); s[1] = pk2(p[0][2], p[0][3]);
  s[2] = pk2(p[1][0], p[1][1]); s[3] = pk2(p[1][2], p[1][3]);
  *(uint4v*)d0 = s;
  s[0] = pk2(p[2][0], p[2][1]); s[1] = pk2(p[2][2], p[2][3]);
  s[2] = pk2(p[3][0], p[3][1]); s[3] = pk2(p[3][2], p[3][3]);
  *(uint4v*)d1 = s;
}

// ---------------- W transpose + bf16: Wt[z][n][k], z=0:WK z=1:WV ------------
__global__ __launch_bounds__(256) void wt_kernel(
    const float* __restrict__ WK, const float* __restrict__ WV,
    short* __restrict__ Wt)
{
  const int z = blockIdx.z;
  const float* W = (z == 0) ? WK : WV;
  short* o = Wt + (size_t)z * 512 * 512;
  __shared__ short t[64][65];
  const int k0 = blockIdx.y * 64, n0 = blockIdx.x * 64;
  const int c = threadIdx.x & 63, rb = threadIdx.x >> 6;
#pragma unroll
  for (int p = 0; p < 16; ++p) {
    const int kk = p * 4 + rb;
    t[kk][c] = f2bf(W[(size_t)(k0 + kk) * 512 + n0 + c]);
  }
  __syncthreads();
#pragma unroll
  for (int p = 0; p < 16; ++p) {
    const int nn = p * 4 + rb;
    o[(size_t)(n0 + nn) * 512 + k0 + c] = t[c][nn];
  }
}

// ============ 8-phase 256x256 K=512 GEMM: K/V projection =====================
__global__ __launch_bounds__(512, 2) void proj_kernel(
    const float* __restrict__ Kin, const float* __restrict__ Vin,
    const short* __restrict__ Wt,
    const float* __restrict__ bK, const float* __restrict__ bV,
    short* __restrict__ kp, short* __restrict__ vp)
{
  const int phys = blockIdx.x;
  const int log_ = (phys & 7) * 64 + (phys >> 3);     // 512 = 8*64 bijective
  const int z = log_ >> 8;
  const int rem = log_ & 255;
  const int row0 = (rem >> 1) * 256;
  const int col0 = (rem & 1) * 256;

  const float* X    = (z == 0) ? Kin : Vin;
  const float* bias = (z == 0) ? bK  : bV;
  const short* Wz   = Wt + (size_t)z * 512 * 512;
  short* dst        = (z == 0) ? kp : vp;

  __shared__ short a_lds[2][256 * 64];   // 64 KB
  __shared__ short b_lds[2][256 * 64];   // 64 KB

  const int tid = threadIdx.x;
  const int lane = tid & 63, wv = tid >> 6;
  const int wr = wv >> 2, wc = wv & 3;                // wave C tile 128x64
  const int fr = lane & 15, fg = lane >> 4;
  const int sxm = fr & 7;

  // A staging: 4 threads/row, 16 f32 each (row 0..127 per half)
  const int arow = tid >> 2, aseg = tid & 3;
  const float* abase = X + (size_t)(row0 + arow) * 512 + aseg * 16;
  const int awo0 = arow * 64 + (((aseg * 2 + 0) ^ (arow & 7)) * 8);
  const int awo1 = arow * 64 + (((aseg * 2 + 1) ^ (arow & 7)) * 8);

  // B staging: per wave 2 gl_lds per half (8 rows x 8 slots each)
  const int brr = wv * 16 + (lane >> 3);
  const int bso = ((lane & 7) ^ ((lane >> 3) & 7)) * 8;   // pre-swizzled source
  const int bdo = (wv * 16) * 64 + lane * 8;              // linear LDS dest

  f32x4 acc[8][4];
#pragma unroll
  for (int i = 0; i < 8; ++i)
#pragma unroll
    for (int j = 0; j < 4; ++j) acc[i][j] = (f32x4){0.f, 0.f, 0.f, 0.f};

  f32x4 pA0[4], pA1[4];

  // ---- prologue: stage tile 0 -> buf 0 (B glds first so cvt's auto-vmcnt drains them)
  {
#pragma unroll
    for (int hh = 0; hh < 2; ++hh)
#pragma unroll
      for (int j = 0; j < 2; ++j)
        gl_lds16(Wz + (size_t)(col0 + hh * 128 + brr + j * 8) * 512 + bso,
                 &b_lds[0][bdo + (hh * 128 + j * 8) * 64]);
#pragma unroll
    for (int j = 0; j < 4; ++j) pA0[j] = *(const f32x4*)(abase + j * 4);
#pragma unroll
    for (int j = 0; j < 4; ++j) pA1[j] = *(const f32x4*)(abase + (size_t)128 * 512 + j * 4);
    cvt16(pA0, &a_lds[0][awo0], &a_lds[0][awo1]);
    cvt16(pA1, &a_lds[0][awo0 + 128 * 64], &a_lds[0][awo1 + 128 * 64]);
  }
  asm volatile("s_waitcnt lgkmcnt(0)" ::: "memory");
  __builtin_amdgcn_s_barrier();

  for (int i = 0; i < 4; ++i) {
#pragma unroll
    for (int h = 0; h < 2; ++h) {
      const int st = 2 * i + h + 1;     // tile staged during this half
      const bool dost = (st < 8);
      const int sb = st & 1;            // == h^1
      const short* ab = &a_lds[h][0];
      const short* bb = &b_lds[h][0];
#pragma unroll
      for (int q = 0; q < 4; ++q) {
        // --- phase q: ds_read quadrant of tile (buf h)
        short8 af[2][4], bf[2][2];
#pragma unroll
        for (int kk = 0; kk < 2; ++kk) {
          const int so = (((kk << 2) | fg) ^ sxm) * 8;
#pragma unroll
          for (int ni = 0; ni < 2; ++ni)
            bf[kk][ni] = *(const short8*)&bb[(wc * 64 + (q & 1) * 32 + ni * 16 + fr) * 64 + so];
#pragma unroll
          for (int mi = 0; mi < 4; ++mi)
            af[kk][mi] = *(const short8*)&ab[(wr * 128 + (q >> 1) * 64 + mi * 16 + fr) * 64 + so];
        }
        // --- stage slot for this phase
        bool wrote = false;
        if (dost) {
          if (q == 0) {
#pragma unroll
            for (int hh = 0; hh < 2; ++hh)
#pragma unroll
              for (int j = 0; j < 2; ++j)
                gl_lds16(Wz + (size_t)(col0 + hh * 128 + brr + j * 8) * 512 + st * 64 + bso,
                         &b_lds[sb][bdo + (hh * 128 + j * 8) * 64]);
#pragma unroll
            for (int j = 0; j < 4; ++j)
              pA0[j] = *(const f32x4*)(abase + st * 64 + j * 4);
          } else if (q == 1) {
#pragma unroll
            for (int j = 0; j < 4; ++j)
              pA1[j] = *(const f32x4*)(abase + (size_t)128 * 512 + st * 64 + j * 4);
          } else if (q == 2) {
            cvt16(pA0, &a_lds[sb][awo0], &a_lds[sb][awo1]);      // auto-vmcnt drains B glds too
            wrote = true;
          } else {
            cvt16(pA1, &a_lds[sb][awo0 + 128 * 64], &a_lds[sb][awo1 + 128 * 64]);
            wrote = true;
          }
        }
        if (wrote) asm volatile("s_waitcnt lgkmcnt(0)" ::: "memory");
        __builtin_amdgcn_s_barrier();
        __builtin_amdgcn_s_setprio(1);
#pragma unroll
        for (int kk = 0; kk < 2; ++kk)
#pragma unroll
          for (int mi = 0; mi < 4; ++mi)
#pragma unroll
            for (int ni = 0; ni < 2; ++ni)
              acc[(q >> 1) * 4 + mi][(q & 1) * 2 + ni] =
                  __builtin_amdgcn_mfma_f32_16x16x32_bf16(
                      af[kk][mi], bf[kk][ni], acc[(q >> 1) * 4 + mi][(q & 1) * 2 + ni], 0, 0, 0);
        __builtin_amdgcn_s_setprio(0);
        __builtin_amdgcn_s_barrier();
      }
    }
  }

#pragma unroll
  for (int ni = 0; ni < 4; ++ni) {
    const int gc = col0 + wc * 64 + ni * 16 + fr;
    const float bv = bias[gc];
#pragma unroll
    for (int mi = 0; mi < 8; ++mi) {
#pragma unroll
      for (int r = 0; r < 4; ++r) {
        const int gr = row0 + wr * 128 + mi * 16 + fg * 4 + r;
        dst[(size_t)gr * 512 + gc] = f2bf(acc[mi][ni][r] + bv);
      }
    }
  }
}

// ---------------- LN + ktv accumulation (unchanged) -------------------------
#define SC 256
#define TP 264

__global__ __launch_bounds__(256) void ktv_kernel(
    const short* __restrict__ kp, const short* __restrict__ vp,
    const float* __restrict__ pos,
    const float* __restrict__ lnwK, const float* __restrict__ lnbK,
    const float* __restrict__ lnwV, const float* __restrict__ lnbV,
    float* __restrict__ ktv)
{
  const int nh = blockIdx.y;
  const int n = nh >> 4, h = nh & 15;
  const int s0 = blockIdx.x * SC;
  const int tid = threadIdx.x;

  __shared__ short klds[48 * TP];
  __shared__ short vlds[48 * TP];
  __shared__ float lw[2][32], lb[2][32];

  if (tid < 32) {
    lw[0][tid] = lnwK[h * 32 + tid]; lb[0][tid] = lnbK[h * 32 + tid];
    lw[1][tid] = lnwV[h * 32 + tid]; lb[1][tid] = lnbV[h * 32 + tid];
  }
  __syncthreads();

  const size_t rowix = (size_t)n * 8192 + (s0 + tid);
  {
    const short8* src = (const short8*)(kp + rowix * 512 + h * 32);
    short8 r0 = src[0], r1 = src[1], r2 = src[2], r3 = src[3];
    float x[32];
#pragma unroll
    for (int i = 0; i < 8; ++i) { x[i] = bf2f(r0[i]); x[8+i] = bf2f(r1[i]); x[16+i] = bf2f(r2[i]); x[24+i] = bf2f(r3[i]); }
    float mu = 0.f;
#pragma unroll
    for (int i = 0; i < 32; ++i) mu += x[i];
    mu *= (1.f / 32.f);
    float var = 0.f;
#pragma unroll
    for (int i = 0; i < 32; ++i) { float d = x[i] - mu; var += d * d; }
    var *= (1.f / 32.f);
    const float rstd = rsqrtf(var + 1e-5f);
#pragma unroll
    for (int d = 0; d < 32; ++d)
      klds[d * TP + tid] = f2bf((x[d] - mu) * rstd * lw[0][d] + lb[0][d]);
  }
  {
    const short8* src = (const short8*)(vp + rowix * 512 + h * 32);
    short8 r0 = src[0], r1 = src[1], r2 = src[2], r3 = src[3];
    float x[32];
#pragma unroll
    for (int i = 0; i < 8; ++i) { x[i] = bf2f(r0[i]); x[8+i] = bf2f(r1[i]); x[16+i] = bf2f(r2[i]); x[24+i] = bf2f(r3[i]); }
    float mu = 0.f;
#pragma unroll
    for (int i = 0; i < 32; ++i) mu += x[i];
    mu *= (1.f / 32.f);
    float var = 0.f;
#pragma unroll
    for (int i = 0; i < 32; ++i) { float d = x[i] - mu; var += d * d; }
    var *= (1.f / 32.f);
    const float rstd = rsqrtf(var + 1e-5f);
#pragma unroll
    for (int d = 0; d < 32; ++d)
      vlds[d * TP + tid] = f2bf((x[d] - mu) * rstd * lw[1][d] + lb[1][d]);
  }
  {
    const short p0 = f2bf(pos[rowix * 2]);
    const short p1 = f2bf(pos[rowix * 2 + 1]);
    klds[32 * TP + tid] = p0; klds[33 * TP + tid] = p1;
    vlds[32 * TP + tid] = p0; vlds[33 * TP + tid] = p1;
  }
  __syncthreads();

  const int wv = tid >> 6, lane = tid & 63;
  if (wv < 3) {
    const int fr = lane & 15, fg = lane >> 4;
    f32x4 acc[3];
#pragma unroll
    for (int i = 0; i < 3; ++i) acc[i] = (f32x4){0.f, 0.f, 0.f, 0.f};
    for (int kk = 0; kk < SC; kk += 32) {
      short8 a = *(const short8*)&klds[(wv * 16 + fr) * TP + kk + fg * 8];
#pragma unroll
      for (int ni = 0; ni < 3; ++ni) {
        short8 b = *(const short8*)&vlds[(ni * 16 + fr) * TP + kk + fg * 8];
        acc[ni] = __builtin_amdgcn_mfma_f32_16x16x32_bf16(a, b, acc[ni], 0, 0, 0);
      }
    }
#pragma unroll
    for (int ni = 0; ni < 3; ++ni) {
      const int ei = ni * 16 + fr;
      if (ei < 34) {
        const int er = (ei < 32) ? ei + 2 : ei - 32;
#pragma unroll
        for (int r = 0; r < 4; ++r) {
          const int di = wv * 16 + fg * 4 + r;
          if (di < 34) {
            const int dr = (di < 32) ? di + 2 : di - 32;
            atomicAdd(&ktv[((size_t)nh * 34 + dr) * 34 + er], acc[ni][r]);
          }
        }
      }
    }
  }
}

// ---- S-build (regridded 64x4): St[n][o][h*32+j], Pp3 accumulators ----------
__global__ __launch_bounds__(256) void sbuild_kernel(
    const float* __restrict__ ktv, const float* __restrict__ fcW,
    const float* __restrict__ bQ, float* __restrict__ St, float* __restrict__ Pp3)
{
  const int nh = blockIdx.x;
  const int n = nh >> 4, h = nh & 15;
  const int jq = blockIdx.y;            // 0..3 (8 j's each)
  __shared__ float g[34 * 34];
  __shared__ float bq8[8];
  for (int i = threadIdx.x; i < 34 * 34; i += 256)
    g[i] = ktv[(size_t)nh * 34 * 34 + i] * (1.f / 8192.f);
  if (threadIdx.x < 8) bq8[threadIdx.x] = bQ[h * 32 + jq * 8 + threadIdx.x];
  __syncthreads();

  for (int o = threadIdx.x; o < 512; o += 256) {
    float wcol[34];
#pragma unroll
    for (int e = 0; e < 34; ++e) wcol[e] = fcW[(size_t)o * 544 + h * 34 + e];
    float rv = 0.f;
    float* srow = St + ((size_t)n * 512 + o) * 512 + h * 32 + jq * 8;
#pragma unroll
    for (int jj = 0; jj < 8; ++jj) {
      const int j = jq * 8 + jj;
      float s = 0.f;
#pragma unroll
      for (int e = 0; e < 34; ++e) s += g[(j + 2) * 34 + e] * wcol[e];
      srow[jj] = s;
      rv += bq8[jj] * s;
    }
    atomicAdd(&Pp3[((size_t)n * 3 + 2) * 512 + o], rv);
    if (jq == 0) {
      float p0 = 0.f, p1 = 0.f;
#pragma unroll
      for (int e = 0; e < 34; ++e) { p0 += g[e] * wcol[e]; p1 += g[34 + e] * wcol[e]; }
      atomicAdd(&Pp3[((size_t)n * 3 + 0) * 512 + o], p0);
      atomicAdd(&Pp3[((size_t)n * 3 + 1) * 512 + o], p1);
    }
  }
}

// ---- C-build: Ct[n][o][k] = sum_m St[n][o][m] * WQ[k][m], bf16 out ---------
__global__ __launch_bounds__(256) void cbuild_kernel(
    const float* __restrict__ St, const float* __restrict__ WQ,
    short* __restrict__ Ct)
{
  const int n = blockIdx.z;
  const int row0 = blockIdx.y * 128;   // o
  const int col0 = blockIdx.x * 128;   // k
  const float* A = St + (size_t)n * 512 * 512;
  const float* B = WQ;

  __shared__ short a_lds[128 * 32];
  __shared__ short b_lds[128 * 32];

  const int tid = threadIdx.x;
  const int lane = tid & 63, wv = tid >> 6;
  const int wr = wv >> 1, wc = wv & 1;
  const int fr = lane & 15, fg = lane >> 4;
  const int ar = tid >> 1, ak = (tid & 1) * 16;

  f32x4 acc[4][4];
#pragma unroll
  for (int i = 0; i < 4; ++i)
#pragma unroll
    for (int j = 0; j < 4; ++j) acc[i][j] = (f32x4){0.f, 0.f, 0.f, 0.f};

  for (int k0 = 0; k0 < 512; k0 += 32) {
    __syncthreads();
    {
      const f32x4* ap = (const f32x4*)(A + (size_t)(row0 + ar) * 512 + k0 + ak);
      f32x4 f0 = ap[0], f1 = ap[1], f2 = ap[2], f3 = ap[3];
      uint4v s0, s1;
      s0[0] = pk2(f0[0], f0[1]); s0[1] = pk2(f0[2], f0[3]);
      s0[2] = pk2(f1[0], f1[1]); s0[3] = pk2(f1[2], f1[3]);
      s1[0] = pk2(f2[0], f2[1]); s1[1] = pk2(f2[2], f2[3]);
      s1[2] = pk2(f3[0], f3[1]); s1[3] = pk2(f3[2], f3[3]);
      *(uint4v*)&a_lds[ar * 32 + ak] = s0;
      *(uint4v*)&a_lds[ar * 32 + ak + 8] = s1;
      const f32x4* bp = (const f32x4*)(B + (size_t)(col0 + ar) * 512 + k0 + ak);
      f32x4 g0 = bp[0], g1 = bp[1], g2 = bp[2], g3 = bp[3];
      s0[0] = pk2(g0[0], g0[1]); s0[1] = pk2(g0[2], g0[3]);
      s0[2] = pk2(g1[0], g1[1]); s0[3] = pk2(g1[2], g1[3]);
      s1[0] = pk2(g2[0], g2[1]); s1[1] = pk2(g2[2], g2[3]);
      s1[2] = pk2(g3[0], g3[1]); s1[3] = pk2(g3[2], g3[3]);
      *(uint4v*)&b_lds[ar * 32 + ak] = s0;
      *(uint4v*)&b_lds[ar * 32 + ak + 8] = s1;
    }
    __syncthreads();

    short8 af[4], bfr[4];
#pragma unroll
    for (int mi = 0; mi < 4; ++mi)
      af[mi] = *(const short8*)&a_lds[(wr * 64 + mi * 16 + fr) * 32 + fg * 8];
#pragma unroll
    for (int ni = 0; ni < 4; ++ni)
      bfr[ni] = *(const short8*)&b_lds[(wc * 64 + ni * 16 + fr) * 32 + fg * 8];
#pragma unroll
    for (int mi = 0; mi < 4; ++mi)
#pragma unroll
      for (int ni = 0; ni < 4; ++ni)
        acc[mi][ni] = __builtin_amdgcn_mfma_f32_16x16x32_bf16(af[mi], bfr[ni], acc[mi][ni], 0, 0, 0);
  }

#pragma unroll
  for (int ni = 0; ni < 4; ++ni) {
    const int gc = col0 + wc * 64 + ni * 16 + fr;
#pragma unroll
    for (int mi = 0; mi < 4; ++mi)
#pragma unroll
      for (int r = 0; r < 4; ++r) {
        const int gr = row0 + wr * 64 + mi * 16 + fg * 4 + r;
        Ct[((size_t)n * 512 + gr) * 512 + gc] = f2bf(acc[mi][ni][r]);
      }
  }
}

// ============ 8-phase fused final GEMM: out = Q@C + pos terms ================
__global__ __launch_bounds__(512, 2) void fuse_kernel(
    const float* __restrict__ Q, const short* __restrict__ Ct,
    const float* __restrict__ pos, const float* __restrict__ Pp3,
    const float* __restrict__ fcb, float* __restrict__ out)
{
  const int phys = blockIdx.x;
  const int log_ = (phys & 7) * 32 + (phys >> 3);     // 256 = 8*32
  const int n = log_ >> 6;
  const int rem = log_ & 63;
  const int row0 = (rem >> 1) * 256;
  const int col0 = (rem & 1) * 256;

  const float* X = Q + (size_t)n * 8192 * 512;
  const short* Bz = Ct + (size_t)n * 512 * 512;

  __shared__ short a_lds[2][256 * 64];
  __shared__ short b_lds[2][256 * 64];

  const int tid = threadIdx.x;
  const int lane = tid & 63, wv = tid >> 6;
  const int wr = wv >> 2, wc = wv & 3;
  const int fr = lane & 15, fg = lane >> 4;
  const int sxm = fr & 7;

  const int arow = tid >> 2, aseg = tid & 3;
  const float* abase = X + (size_t)(row0 + arow) * 512 + aseg * 16;
  const int awo0 = arow * 64 + (((aseg * 2 + 0) ^ (arow & 7)) * 8);
  const int awo1 = arow * 64 + (((aseg * 2 + 1) ^ (arow & 7)) * 8);

  const int brr = wv * 16 + (lane >> 3);
  const int bso = ((lane & 7) ^ ((lane >> 3) & 7)) * 8;
  const int bdo = (wv * 16) * 64 + lane * 8;

  f32x4 acc[8][4];
#pragma unroll
  for (int i = 0; i < 8; ++i)
#pragma unroll
    for (int j = 0; j < 4; ++j) acc[i][j] = (f32x4){0.f, 0.f, 0.f, 0.f};

  f32x4 pA0[4], pA1[4];

  {
#pragma unroll
    for (int hh = 0; hh < 2; ++hh)
#pragma unroll
      for (int j = 0; j < 2; ++j)
        gl_lds16(Bz + (size_t)(col0 + hh * 128 + brr + j * 8) * 512 + bso,
                 &b_lds[0][bdo + (hh * 128 + j * 8) * 64]);
#pragma unroll
    for (int j = 0; j < 4; ++j) pA0[j] = *(const f32x4*)(abase + j * 4);
#pragma unroll
    for (int j = 0; j < 4; ++j) pA1[j] = *(const f32x4*)(abase + (size_t)128 * 512 + j * 4);
    cvt16(pA0, &a_lds[0][awo0], &a_lds[0][awo1]);
    cvt16(pA1, &a_lds[0][awo0 + 128 * 64], &a_lds[0][awo1 + 128 * 64]);
  }
  asm volatile("s_waitcnt lgkmcnt(0)" ::: "memory");
  __builtin_amdgcn_s_barrier();

  for (int i = 0; i < 4; ++i) {
#pragma unroll
    for (int h = 0; h < 2; ++h) {
      const int st = 2 * i + h + 1;
      const bool dost = (st < 8);
      const int sb = st & 1;
      const short* ab = &a_lds[h][0];
      const short* bb = &b_lds[h][0];
#pragma unroll
      for (int q = 0; q < 4; ++q) {
        short8 af[2][4], bf[2][2];
#pragma unroll
        for (int kk = 0; kk < 2; ++kk) {
          const int so = (((kk << 2) | fg) ^ sxm) * 8;
#pragma unroll
          for (int ni = 0; ni < 2; ++ni)
            bf[kk][ni] = *(const short8*)&bb[(wc * 64 + (q & 1) * 32 + ni * 16 + fr) * 64 + so];
#pragma unroll
          for (int mi = 0; mi < 4; ++mi)
            af[kk][mi] = *(const short8*)&ab[(wr * 128 + (q >> 1) * 64 + mi * 16 + fr) * 64 + so];
        }
        bool wrote = false;
        if (dost) {
          if (q == 0) {
#pragma unroll
            for (int hh = 0; hh < 2; ++hh)
#pragma unroll
              for (int j = 0; j < 2; ++j)
                gl_lds16(Bz + (size_t)(col0 + hh * 128 + brr + j * 8) * 512 + st * 64 + bso,
                         &b_lds[sb][bdo + (hh * 128 + j * 8) * 64]);
#pragma unroll
            for (int j = 0; j < 4; ++j)
              pA0[j] = *(const f32x4*)(abase + st * 64 + j * 4);
          } else if (q == 1) {
#pragma unroll
            for (int j = 0; j < 4; ++j)
              pA1[j] = *(const f32x4*)(abase + (size_t)128 * 512 + st * 64 + j * 4);
          } else if (q == 2) {
            cvt16(pA0, &a_lds[sb][awo0], &a_lds[sb][awo1]);
            wrote = true;
          } else {
            cvt16(pA1, &a_lds[sb][awo0 + 128 * 64], &a_lds[sb][awo1 + 128 * 64]);
            wrote = true;
          }
        }
        if (wrote) asm volatile("s_waitcnt lgkmcnt(0)" ::: "memory");
        __builtin_amdgcn_s_barrier();
        __builtin_amdgcn_s_setprio(1);
#pragma unroll
        for (int kk = 0; kk < 2; ++kk)
#pragma unroll
          for (int mi = 0; mi < 4; ++mi)
#pragma unroll
            for (int ni = 0; ni < 2; ++ni)
              acc[(q >> 1) * 4 + mi][(q & 1) * 2 + ni] =
                  __builtin_amdgcn_mfma_f32_16x16x32_bf16(
                      af[kk][mi], bf[kk][ni], acc[(q >> 1) * 4 + mi][(q & 1) * 2 + ni], 0, 0, 0);
        __builtin_amdgcn_s_setprio(0);
        __builtin_amdgcn_s_barrier();
      }
    }
  }

  // epilogue: + pos-term + bQ-term + fc_b
  float pp0[4], pp1[4], rv[4];
#pragma unroll
  for (int ni = 0; ni < 4; ++ni) {
    const int gc = col0 + wc * 64 + ni * 16 + fr;
    pp0[ni] = Pp3[((size_t)n * 3 + 0) * 512 + gc];
    pp1[ni] = Pp3[((size_t)n * 3 + 1) * 512 + gc];
    rv[ni]  = Pp3[((size_t)n * 3 + 2) * 512 + gc] + fcb[gc];
  }
#pragma unroll
  for (int mi = 0; mi < 8; ++mi) {
#pragma unroll
    for (int r = 0; r < 4; ++r) {
      const int gr = row0 + wr * 128 + mi * 16 + fg * 4 + r;
      const float* pr = pos + ((size_t)n * 8192 + gr) * 2;
      const float q0 = pr[0], q1 = pr[1];
#pragma unroll
      for (int ni = 0; ni < 4; ++ni) {
        const int gc = col0 + wc * 64 + ni * 16 + fr;
        out[((size_t)n * 8192 + gr) * 512 + gc] =
            acc[mi][ni][r] + pp0[ni] * q0 + pp1[ni] * q1 + rv[ni];
      }
    }
  }
}

// ---------------------------------------------------------------------------
extern "C" void kernel_launch(void* const* d_in, const int* in_sizes, int n_in,
                              void* d_out, int out_size, void* d_ws, size_t ws_size,
                              hipStream_t stream) {
  const float* Q    = (const float*)d_in[0];
  const float* Kin  = (const float*)d_in[1];
  const float* Vin  = (const float*)d_in[2];
  const float* pos  = (const float*)d_in[3];
  const float* WQ   = (const float*)d_in[4];
  const float* WK   = (const float*)d_in[5];
  const float* WV   = (const float*)d_in[6];
  const float* bQ   = (const float*)d_in[7];
  const float* bK   = (const float*)d_in[8];
  const float* bV   = (const float*)d_in[9];
  const float* lnwK = (const float*)d_in[10];
  const float* lnbK = (const float*)d_in[11];
  const float* lnwV = (const float*)d_in[12];
  const float* lnbV = (const float*)d_in[13];
  const float* fcW  = (const float*)d_in[14];
  const float* fcb  = (const float*)d_in[15];

  char* ws = (char*)d_ws;
  const size_t KP_B  = (size_t)4 * 8192 * 512 * 2;   // 33,554,432
  const size_t KTV_B = (size_t)64 * 34 * 34 * 4;     //    295,936
  const size_t ST_B  = (size_t)4 * 512 * 512 * 4;    //  4,194,304
  const size_t CT_B  = (size_t)4 * 512 * 512 * 2;    //  2,097,152
  const size_t WT_B  = (size_t)2 * 512 * 512 * 2;    //  1,048,576
  const size_t PP_B  = (size_t)4 * 3 * 512 * 4;      //     24,576
  short* kp  = (short*)ws;
  short* vp  = (short*)(ws + KP_B);
  float* ktv = (float*)(ws + 2 * KP_B);
  float* St  = (float*)(ws + 2 * KP_B + KTV_B);
  short* Ct  = (short*)(ws + 2 * KP_B + KTV_B + ST_B);
  short* Wt  = (short*)(ws + 2 * KP_B + KTV_B + ST_B + CT_B);
  float* Pp3 = (float*)(ws + 2 * KP_B + KTV_B + ST_B + CT_B + WT_B);

  (void)hipMemsetAsync(ktv, 0, KTV_B, stream);
  (void)hipMemsetAsync(Pp3, 0, PP_B, stream);
  hipLaunchKernelGGL(wt_kernel, dim3(8, 8, 2), dim3(256), 0, stream, WK, WV, Wt);
  hipLaunchKernelGGL(proj_kernel, dim3(512), dim3(512), 0, stream,
                     Kin, Vin, Wt, bK, bV, kp, vp);
  hipLaunchKernelGGL(ktv_kernel, dim3(32, 64), dim3(256), 0, stream,
                     kp, vp, pos, lnwK, lnbK, lnwV, lnbV, ktv);
  hipLaunchKernelGGL(sbuild_kernel, dim3(64, 4), dim3(256), 0, stream,
                     ktv, fcW, bQ, St, Pp3);
  hipLaunchKernelGGL(cbuild_kernel, dim3(4, 4, 4), dim3(256), 0, stream,
                     St, WQ, Ct);
  hipLaunchKernelGGL(fuse_kernel, dim3(256), dim3(512), 0, stream,
                     Q, Ct, pos, Pp3, fcb, (float*)d_out);
}